// Round 6
// baseline (361.556 us; speedup 1.0000x reference)
//
#include <hip/hip_runtime.h>
#include <math.h>

// ---------------------------------------------------------------------------
// PointSampler / DevConv, CSR-gather with bucketed (write-coalesced) CSR build.
//   per layer l: y = h @ Cl.T  (f32) + y16 (fp16 copy, gather operand)
//                agg[i] = deg>0 ? (max_{j in N(i)} y16[j]) - y[i] : 0
//   head (fused into 3rd gather): out[i] = sigmoid( agg3[i] . v + b )
// max over fp16-rounded values via v_pk_max_f16 (packed, no unpack in loop);
// subtraction + GEMM chain stay f32.
// ---------------------------------------------------------------------------

#define WBITS 9
#define WNODES 512            // nodes per bucket
#define MAXNB 256             // max buckets (requires N <= 131072, src < 2^17)
#define CHUNK 8192            // edges per partA/hist block
#define STG_CAP 12288         // partB LDS staging entries (48 KB)

#define PKNINF 0xFC00FC00u    // packed fp16 (-inf, -inf)

typedef __fp16 h2v __attribute__((ext_vector_type(2)));

__device__ __forceinline__ unsigned pkmax(unsigned a, unsigned b) {
    unsigned r;
    asm("v_pk_max_f16 %0, %1, %2" : "=v"(r) : "v"(a), "v"(b));
    return r;
}
__device__ __forceinline__ unsigned pkrtz(float a, float b) {
    h2v r = __builtin_amdgcn_cvt_pkrtz(a, b);
    return *reinterpret_cast<unsigned*>(&r);
}
__device__ __forceinline__ float h2lo(unsigned u) {
    h2v h = *reinterpret_cast<h2v*>(&u);
    return (float)h.x;
}
__device__ __forceinline__ float h2hi(unsigned u) {
    h2v h = *reinterpret_cast<h2v*>(&u);
    return (float)h.y;
}

// block 0: C2 = Wp[1]@Wt[0];  block 1: C3 = Wp[2]@Wt[1];  block 2: v = Wout@Wt[2]
__global__ __launch_bounds__(256) void prep_k(
    const float* __restrict__ Wp, const float* __restrict__ Wt,
    const float* __restrict__ Wout,
    float* __restrict__ C2, float* __restrict__ C3, float* __restrict__ vout)
{
    __shared__ float A[4096];
    __shared__ float B[4096];
    int tid = threadIdx.x;
    int b = blockIdx.x;
    if (b < 2) {
        const float* Ap = Wp + (size_t)(b + 1) * 4096;
        const float* Bp = Wt + (size_t)b * 4096;
        for (int i = tid; i < 4096; i += 256) { A[i] = Ap[i]; B[i] = Bp[i]; }
        __syncthreads();
        float* C = b ? C3 : C2;
        for (int i = tid; i < 4096; i += 256) {
            int d = i >> 6, k = i & 63;
            float s = 0.f;
            #pragma unroll
            for (int m = 0; m < 64; ++m) s += A[d * 64 + m] * B[m * 64 + k];
            C[i] = s;
        }
    } else {
        for (int i = tid; i < 4096; i += 256) A[i] = Wt[2 * 4096 + i];
        if (tid < 64) B[tid] = Wout[tid];
        __syncthreads();
        if (tid < 64) {
            float s = 0.f;
            #pragma unroll
            for (int m = 0; m < 64; ++m) s += B[m] * A[m * 64 + tid];
            vout[tid] = s;
        }
    }
}

__global__ __launch_bounds__(256) void clear_int_k(int* __restrict__ p, int n)
{
    int i = blockIdx.x * 256 + threadIdx.x;
    if (i < n) p[i] = 0;
}

// per-chunk LDS histogram of dst buckets -> global bucket counts
__global__ __launch_bounds__(256) void bucket_hist_k(
    const int* __restrict__ eidx, int* __restrict__ bcnt, int E, int NB)
{
    __shared__ int h[MAXNB];
    int tid = threadIdx.x;
    for (int i = tid; i < NB; i += 256) h[i] = 0;
    __syncthreads();
    int start = blockIdx.x * CHUNK;
    int end = min(E, start + CHUNK);
    for (int e = start + tid; e < end; e += 256)
        atomicAdd(&h[eidx[E + e] >> WBITS], 1);
    __syncthreads();
    for (int i = tid; i < NB; i += 256)
        if (h[i]) atomicAdd(&bcnt[i], h[i]);
}

// 1-block scan of bucket counts -> bbase (exclusive), init gcur, row_ptr[N]=E
__global__ __launch_bounds__(256) void bucket_scan_k(
    const int* __restrict__ bcnt, int* __restrict__ bbase,
    int* __restrict__ gcur, int* __restrict__ row_ptr, int NB, int N, int E)
{
    __shared__ int sA[MAXNB], sB[MAXNB];
    int tid = threadIdx.x;
    int v0 = (tid < NB) ? bcnt[tid] : 0;
    sA[tid] = v0;
    __syncthreads();
    int* sp = sA; int* dp = sB;
    for (int off = 1; off < MAXNB; off <<= 1) {
        dp[tid] = sp[tid] + ((tid >= off) ? sp[tid - off] : 0);
        __syncthreads();
        int* t = sp; sp = dp; dp = t;
    }
    if (tid < NB) {
        int ex = sp[tid] - v0;
        bbase[tid] = ex;
        gcur[tid]  = ex;
    }
    if (tid == 0) {
        bbase[NB]  = E;
        row_ptr[N] = E;
    }
}

// partition edges into bucket-major order (packed src | dstLow<<17)
__global__ __launch_bounds__(256) void partA_k(
    const int* __restrict__ eidx, int* __restrict__ gcur,
    int* __restrict__ B1, int E, int NB)
{
    __shared__ int hist[MAXNB];
    __shared__ int lofs[MAXNB];
    __shared__ int lcur[MAXNB];
    __shared__ int gofs[MAXNB];
    __shared__ int sA[MAXNB], sB[MAXNB];
    __shared__ int stg_val[CHUNK];
    __shared__ int stg_pos[CHUNK];
    int tid = threadIdx.x;
    int start = blockIdx.x * CHUNK;
    int cnt = min(E - start, CHUNK);
    if (cnt <= 0) return;

    for (int i = tid; i < NB; i += 256) hist[i] = 0;
    __syncthreads();

    int es[CHUNK / 256], ed[CHUNK / 256];
    #pragma unroll
    for (int i = 0; i < CHUNK / 256; ++i) {
        int li = i * 256 + tid;
        if (li < cnt) {
            es[i] = eidx[start + li];
            ed[i] = eidx[E + start + li];
            atomicAdd(&hist[ed[i] >> WBITS], 1);
        }
    }
    __syncthreads();
    sA[tid] = (tid < NB) ? hist[tid] : 0;
    __syncthreads();
    int* sp = sA; int* dp = sB;
    for (int off = 1; off < MAXNB; off <<= 1) {
        dp[tid] = sp[tid] + ((tid >= off) ? sp[tid - off] : 0);
        __syncthreads();
        int* t = sp; sp = dp; dp = t;
    }
    if (tid < NB) {
        int c  = hist[tid];
        int ex = sp[tid] - c;
        lofs[tid] = ex;
        lcur[tid] = ex;
        gofs[tid] = c ? atomicAdd(&gcur[tid], c) : 0;
    }
    __syncthreads();
    #pragma unroll
    for (int i = 0; i < CHUNK / 256; ++i) {
        int li = i * 256 + tid;
        if (li < cnt) {
            int b = ed[i] >> WBITS;
            int p = atomicAdd(&lcur[b], 1);
            stg_val[p] = es[i] | ((ed[i] & (WNODES - 1)) << 17);
            stg_pos[p] = gofs[b] + (p - lofs[b]);
        }
    }
    __syncthreads();
    for (int i = tid; i < cnt; i += 256)
        B1[stg_pos[i]] = stg_val[i];
}

// per-bucket: degree count -> scan -> row_ptr; LDS-staged coalesced col scatter
__global__ __launch_bounds__(256) void partB_k(
    const int* __restrict__ B1, const int* __restrict__ bbase,
    int* __restrict__ row_ptr, int* __restrict__ col, int N, int NB)
{
    __shared__ int cnt[WNODES];
    __shared__ int lcur[WNODES];
    __shared__ int sA[WNODES], sB[WNODES];
    __shared__ int stg[STG_CAP];
    int b   = blockIdx.x;
    int tid = threadIdx.x;
    int gb0 = bbase[b], gb1 = bbase[b + 1];
    int m   = gb1 - gb0;
    int nb0 = b << WBITS;

    for (int i = tid; i < WNODES; i += 256) cnt[i] = 0;
    __syncthreads();
    for (int i = tid; i < m; i += 256)
        atomicAdd(&cnt[B1[gb0 + i] >> 17], 1);
    __syncthreads();
    for (int i = tid; i < WNODES; i += 256) sA[i] = cnt[i];
    __syncthreads();
    int* sp = sA; int* dp = sB;
    for (int off = 1; off < WNODES; off <<= 1) {
        for (int i = tid; i < WNODES; i += 256)
            dp[i] = sp[i] + ((i >= off) ? sp[i - off] : 0);
        __syncthreads();
        int* t = sp; sp = dp; dp = t;
    }
    for (int i = tid; i < WNODES; i += 256) {
        int ex = sp[i] - cnt[i];
        lcur[i] = ex;
        int node = nb0 + i;
        if (node < N) row_ptr[node] = gb0 + ex;
    }
    __syncthreads();
    if (m <= STG_CAP) {
        for (int i = tid; i < m; i += 256) {
            int v = B1[gb0 + i];
            int p = atomicAdd(&lcur[v >> 17], 1);
            stg[p] = v & 0x1FFFF;
        }
        __syncthreads();
        for (int i = tid; i < m; i += 256)
            col[gb0 + i] = stg[i];
    } else {               // adversarial-degree fallback (correct, uncoalesced)
        for (int i = tid; i < m; i += 256) {
            int v = B1[gb0 + i];
            int p = atomicAdd(&lcur[v >> 17], 1);
            col[gb0 + p] = v & 0x1FFFF;
        }
    }
}

// ---------------- per-layer kernels ----------------

// y[r][:] = in_row(r) @ C.T (f32) + fp16 copy y16; one thread per row.
__global__ __launch_bounds__(256) void gemm64_k(
    const float* __restrict__ in,
    const float* __restrict__ C,      // [64][64] row-major, C[d][k]
    float* __restrict__ out, unsigned* __restrict__ out16, int n)
{
    __shared__ float sCT[64 * 68];    // sCT[k*68 + d]
    int tid = threadIdx.x;
    for (int i = tid; i < 4096; i += 256) {
        int d = i >> 6, k = i & 63;
        sCT[k * 68 + d] = C[i];
    }
    __syncthreads();
    int r = blockIdx.x * 256 + tid;
    if (r >= n) return;

    float xr[64];
    const float4* xp = (const float4*)(in + (size_t)r * 64);
    #pragma unroll
    for (int k4 = 0; k4 < 16; ++k4) {
        float4 v = xp[k4];
        xr[k4 * 4 + 0] = v.x; xr[k4 * 4 + 1] = v.y;
        xr[k4 * 4 + 2] = v.z; xr[k4 * 4 + 3] = v.w;
    }

    float4* op  = (float4*)(out + (size_t)r * 64);
    uint2*  o16 = (uint2*)(out16 + (size_t)r * 32);
    for (int dg = 0; dg < 16; ++dg) {
        float a0 = 0.f, a1 = 0.f, a2 = 0.f, a3 = 0.f;
        #pragma unroll
        for (int k = 0; k < 64; ++k) {
            float4 c = *(const float4*)&sCT[k * 68 + dg * 4];
            a0 += xr[k] * c.x;
            a1 += xr[k] * c.y;
            a2 += xr[k] * c.z;
            a3 += xr[k] * c.w;
        }
        float4 o; o.x = a0; o.y = a1; o.z = a2; o.w = a3;
        op[dg] = o;
        uint2 p; p.x = pkrtz(a0, a1); p.y = pkrtz(a2, a3);
        o16[dg] = p;
    }
}

// one wave per node. fp16 rows (128B): quarter q handles edge kb+q, lane t=lane&15
// holds components [4t,4t+4) as two packed half2. Max via v_pk_max_f16.
// Quarters merged by shfl_xor(32/16). Subtraction uses exact f32 y_i.
// FINAL fuses the Linear(D,1)+sigmoid head.
template<bool FINAL>
__global__ __launch_bounds__(256) void gather_max_k(
    const int* __restrict__ row_ptr, const int* __restrict__ col,
    const uint2* __restrict__ y16, const float* __restrict__ y,
    float* __restrict__ agg,
    const float* __restrict__ v, const float* __restrict__ bptr,
    float* __restrict__ out, int n)
{
    int gid  = blockIdx.x * 256 + threadIdx.x;
    int node = gid >> 6;
    int lane = threadIdx.x & 63;
    int q    = lane >> 4;           // which of 4 edges in this iteration
    int t    = lane & 15;           // component group [4t, 4t+4)
    if (node >= n) return;
    int beg = row_ptr[node], end = row_ptr[node + 1];

    unsigned c0 = PKNINF, c1 = PKNINF;
    for (int kb = beg; kb < end; kb += 4) {
        int  idx   = kb + q;
        bool valid = idx < end;
        int  j     = col[valid ? idx : beg];      // 16-lane broadcast load
        uint2 val  = y16[(size_t)j * 16 + t];
        unsigned v0 = valid ? val.x : PKNINF;
        unsigned v1 = valid ? val.y : PKNINF;
        c0 = pkmax(c0, v0);
        c1 = pkmax(c1, v1);
    }
    c0 = pkmax(c0, __shfl_xor(c0, 32));
    c1 = pkmax(c1, __shfl_xor(c1, 32));
    c0 = pkmax(c0, __shfl_xor(c0, 16));
    c1 = pkmax(c1, __shfl_xor(c1, 16));

    bool has = end > beg;
    if (!FINAL) {
        if (q == 0) {
            float4 yi = ((const float4*)y)[(size_t)node * 16 + t];
            float4 o;
            o.x = has ? (h2lo(c0) - yi.x) : 0.f;
            o.y = has ? (h2hi(c0) - yi.y) : 0.f;
            o.z = has ? (h2lo(c1) - yi.z) : 0.f;
            o.w = has ? (h2hi(c1) - yi.w) : 0.f;
            ((float4*)agg)[(size_t)node * 16 + t] = o;
        }
    } else {
        float s = 0.f;
        if (q == 0) {
            float4 yi = ((const float4*)y)[(size_t)node * 16 + t];
            float4 vp = ((const float4*)v)[t];
            float g0 = has ? (h2lo(c0) - yi.x) : 0.f;
            float g1 = has ? (h2hi(c0) - yi.y) : 0.f;
            float g2 = has ? (h2lo(c1) - yi.z) : 0.f;
            float g3 = has ? (h2hi(c1) - yi.w) : 0.f;
            s = g0 * vp.x + g1 * vp.y + g2 * vp.z + g3 * vp.w;
        }
        #pragma unroll
        for (int off = 8; off >= 1; off >>= 1)
            s += __shfl_xor(s, off);
        if (lane == 0)
            out[node] = 1.f / (1.f + __expf(-(s + bptr[0])));
    }
}

extern "C" void kernel_launch(void* const* d_in, const int* in_sizes, int n_in,
                              void* d_out, int out_size, void* d_ws, size_t ws_size,
                              hipStream_t stream)
{
    const float* x     = (const float*)d_in[0];
    const int*   edges = (const int*)d_in[1];   // int32 view, [2][E]
    const float* Wp    = (const float*)d_in[2];
    const float* Wt    = (const float*)d_in[3];
    const float* Wout  = (const float*)d_in[4];
    const float* bout  = (const float*)d_in[5];
    const int N = in_sizes[0] / 64;             // 100000
    const int E = in_sizes[1] / 2;              // 1600000
    const int NB = (N + WNODES - 1) >> WBITS;   // 196
    float* out = (float*)d_out;

    char* ws = (char*)d_ws;
    float* y    = (float*)ws; ws += (size_t)N * 64 * 4;
    float* agg  = (float*)ws; ws += (size_t)N * 64 * 4;
    int*   B1   = (int*)agg;                    // alias: B1 dead before agg live
    unsigned* y16 = (unsigned*)ws; ws += (size_t)N * 32 * 4;
    int* col     = (int*)ws; ws += (size_t)(E + 8) * 4;
    int* row_ptr = (int*)ws; ws += (size_t)(N + 4) * 4;
    int* bcnt    = (int*)ws; ws += MAXNB * 4;
    int* bbase   = (int*)ws; ws += (MAXNB + 4) * 4;
    int* gcur    = (int*)ws; ws += MAXNB * 4;
    float* C2 = (float*)ws; ws += 4096 * 4;
    float* C3 = (float*)ws; ws += 4096 * 4;
    float* vv = (float*)ws; ws += 64 * 4;

    const int nodeBlocks   = (N + 255) / 256;
    const int chunkBlocks  = (E + CHUNK - 1) / CHUNK;
    const int gatherBlocks = (N * 64 + 255) / 256;

    prep_k<<<3, 256, 0, stream>>>(Wp, Wt, Wout, C2, C3, vv);

    // CSR build (bucketed, write-coalesced)
    clear_int_k<<<1, 256, 0, stream>>>(bcnt, NB);
    bucket_hist_k<<<chunkBlocks, 256, 0, stream>>>(edges, bcnt, E, NB);
    bucket_scan_k<<<1, 256, 0, stream>>>(bcnt, bbase, gcur, row_ptr, NB, N, E);
    partA_k<<<chunkBlocks, 256, 0, stream>>>(edges, gcur, B1, E, NB);
    partB_k<<<NB, 256, 0, stream>>>(B1, bbase, row_ptr, col, N, NB);

    // layer 1
    gemm64_k<<<nodeBlocks, 256, 0, stream>>>(x, Wp, y, y16, N);
    gather_max_k<false><<<gatherBlocks, 256, 0, stream>>>(row_ptr, col, (const uint2*)y16, y, agg,
                                                          nullptr, nullptr, nullptr, N);
    // layer 2
    gemm64_k<<<nodeBlocks, 256, 0, stream>>>(agg, C2, y, y16, N);
    gather_max_k<false><<<gatherBlocks, 256, 0, stream>>>(row_ptr, col, (const uint2*)y16, y, agg,
                                                          nullptr, nullptr, nullptr, N);
    // layer 3
    gemm64_k<<<nodeBlocks, 256, 0, stream>>>(agg, C3, y, y16, N);
    gather_max_k<true><<<gatherBlocks, 256, 0, stream>>>(row_ptr, col, (const uint2*)y16, y, nullptr,
                                                         vv, bout, out, N);
}

// Round 7
// 308.483 us; speedup vs baseline: 1.1720x; 1.1720x over previous
//
#include <hip/hip_runtime.h>
#include <math.h>

// ---------------------------------------------------------------------------
// PointSampler / DevConv, CSR-gather with bucketed (write-coalesced) CSR build.
//   per layer l: y = h @ Cl.T  (f32) + y16 (fp16 copy, gather operand)
//                agg[i] = deg>0 ? (max_{j in N(i)} y16[j]) - y[i] : 0
//   head (fused into 3rd gather): out[i] = sigmoid( agg3[i] . v + b )
// Gather: col loaded once per 64-edge block (coalesced), indices broadcast via
// shfl; 16-edge unroll gives 4 independent packed-fp16 row loads in flight.
// ---------------------------------------------------------------------------

#define WBITS 9
#define WNODES 512            // nodes per bucket
#define MAXNB 256             // max buckets (requires N <= 131072, src < 2^17)
#define CHUNK 8192            // edges per partA/hist block
#define STG_CAP 12288         // partB LDS staging entries (48 KB)

#define PKNINF 0xFC00FC00u    // packed fp16 (-inf, -inf)

typedef __fp16 h2v __attribute__((ext_vector_type(2)));

__device__ __forceinline__ unsigned pkmax(unsigned a, unsigned b) {
    unsigned r;
    asm("v_pk_max_f16 %0, %1, %2" : "=v"(r) : "v"(a), "v"(b));
    return r;
}
__device__ __forceinline__ unsigned pkrtz(float a, float b) {
    h2v r = __builtin_amdgcn_cvt_pkrtz(a, b);
    return *reinterpret_cast<unsigned*>(&r);
}
__device__ __forceinline__ float h2lo(unsigned u) {
    h2v h = *reinterpret_cast<h2v*>(&u);
    return (float)h.x;
}
__device__ __forceinline__ float h2hi(unsigned u) {
    h2v h = *reinterpret_cast<h2v*>(&u);
    return (float)h.y;
}

// block 0: C2 = Wp[1]@Wt[0];  block 1: C3 = Wp[2]@Wt[1];  block 2: v = Wout@Wt[2]
__global__ __launch_bounds__(256) void prep_k(
    const float* __restrict__ Wp, const float* __restrict__ Wt,
    const float* __restrict__ Wout,
    float* __restrict__ C2, float* __restrict__ C3, float* __restrict__ vout)
{
    __shared__ float A[4096];
    __shared__ float B[4096];
    int tid = threadIdx.x;
    int b = blockIdx.x;
    if (b < 2) {
        const float* Ap = Wp + (size_t)(b + 1) * 4096;
        const float* Bp = Wt + (size_t)b * 4096;
        for (int i = tid; i < 4096; i += 256) { A[i] = Ap[i]; B[i] = Bp[i]; }
        __syncthreads();
        float* C = b ? C3 : C2;
        for (int i = tid; i < 4096; i += 256) {
            int d = i >> 6, k = i & 63;
            float s = 0.f;
            #pragma unroll
            for (int m = 0; m < 64; ++m) s += A[d * 64 + m] * B[m * 64 + k];
            C[i] = s;
        }
    } else {
        for (int i = tid; i < 4096; i += 256) A[i] = Wt[2 * 4096 + i];
        if (tid < 64) B[tid] = Wout[tid];
        __syncthreads();
        if (tid < 64) {
            float s = 0.f;
            #pragma unroll
            for (int m = 0; m < 64; ++m) s += B[m] * A[m * 64 + tid];
            vout[tid] = s;
        }
    }
}

__global__ __launch_bounds__(256) void clear_int_k(int* __restrict__ p, int n)
{
    int i = blockIdx.x * 256 + threadIdx.x;
    if (i < n) p[i] = 0;
}

// per-chunk LDS histogram of dst buckets -> global bucket counts
__global__ __launch_bounds__(256) void bucket_hist_k(
    const int* __restrict__ eidx, int* __restrict__ bcnt, int E, int NB)
{
    __shared__ int h[MAXNB];
    int tid = threadIdx.x;
    for (int i = tid; i < NB; i += 256) h[i] = 0;
    __syncthreads();
    int start = blockIdx.x * CHUNK;
    int end = min(E, start + CHUNK);
    for (int e = start + tid; e < end; e += 256)
        atomicAdd(&h[eidx[E + e] >> WBITS], 1);
    __syncthreads();
    for (int i = tid; i < NB; i += 256)
        if (h[i]) atomicAdd(&bcnt[i], h[i]);
}

// 1-block scan of bucket counts -> bbase (exclusive), init gcur, row_ptr[N]=E
__global__ __launch_bounds__(256) void bucket_scan_k(
    const int* __restrict__ bcnt, int* __restrict__ bbase,
    int* __restrict__ gcur, int* __restrict__ row_ptr, int NB, int N, int E)
{
    __shared__ int sA[MAXNB], sB[MAXNB];
    int tid = threadIdx.x;
    int v0 = (tid < NB) ? bcnt[tid] : 0;
    sA[tid] = v0;
    __syncthreads();
    int* sp = sA; int* dp = sB;
    for (int off = 1; off < MAXNB; off <<= 1) {
        dp[tid] = sp[tid] + ((tid >= off) ? sp[tid - off] : 0);
        __syncthreads();
        int* t = sp; sp = dp; dp = t;
    }
    if (tid < NB) {
        int ex = sp[tid] - v0;
        bbase[tid] = ex;
        gcur[tid]  = ex;
    }
    if (tid == 0) {
        bbase[NB]  = E;
        row_ptr[N] = E;
    }
}

// partition edges into bucket-major order (packed src | dstLow<<17)
__global__ __launch_bounds__(256) void partA_k(
    const int* __restrict__ eidx, int* __restrict__ gcur,
    int* __restrict__ B1, int E, int NB)
{
    __shared__ int hist[MAXNB];
    __shared__ int lofs[MAXNB];
    __shared__ int lcur[MAXNB];
    __shared__ int gofs[MAXNB];
    __shared__ int sA[MAXNB], sB[MAXNB];
    __shared__ int stg_val[CHUNK];
    __shared__ int stg_pos[CHUNK];
    int tid = threadIdx.x;
    int start = blockIdx.x * CHUNK;
    int cnt = min(E - start, CHUNK);
    if (cnt <= 0) return;

    for (int i = tid; i < NB; i += 256) hist[i] = 0;
    __syncthreads();

    int es[CHUNK / 256], ed[CHUNK / 256];
    #pragma unroll
    for (int i = 0; i < CHUNK / 256; ++i) {
        int li = i * 256 + tid;
        if (li < cnt) {
            es[i] = eidx[start + li];
            ed[i] = eidx[E + start + li];
            atomicAdd(&hist[ed[i] >> WBITS], 1);
        }
    }
    __syncthreads();
    sA[tid] = (tid < NB) ? hist[tid] : 0;
    __syncthreads();
    int* sp = sA; int* dp = sB;
    for (int off = 1; off < MAXNB; off <<= 1) {
        dp[tid] = sp[tid] + ((tid >= off) ? sp[tid - off] : 0);
        __syncthreads();
        int* t = sp; sp = dp; dp = t;
    }
    if (tid < NB) {
        int c  = hist[tid];
        int ex = sp[tid] - c;
        lofs[tid] = ex;
        lcur[tid] = ex;
        gofs[tid] = c ? atomicAdd(&gcur[tid], c) : 0;
    }
    __syncthreads();
    #pragma unroll
    for (int i = 0; i < CHUNK / 256; ++i) {
        int li = i * 256 + tid;
        if (li < cnt) {
            int b = ed[i] >> WBITS;
            int p = atomicAdd(&lcur[b], 1);
            stg_val[p] = es[i] | ((ed[i] & (WNODES - 1)) << 17);
            stg_pos[p] = gofs[b] + (p - lofs[b]);
        }
    }
    __syncthreads();
    for (int i = tid; i < cnt; i += 256)
        B1[stg_pos[i]] = stg_val[i];
}

// per-bucket: degree count -> scan -> row_ptr; LDS-staged coalesced col scatter
__global__ __launch_bounds__(256) void partB_k(
    const int* __restrict__ B1, const int* __restrict__ bbase,
    int* __restrict__ row_ptr, int* __restrict__ col, int N, int NB)
{
    __shared__ int cnt[WNODES];
    __shared__ int lcur[WNODES];
    __shared__ int sA[WNODES], sB[WNODES];
    __shared__ int stg[STG_CAP];
    int b   = blockIdx.x;
    int tid = threadIdx.x;
    int gb0 = bbase[b], gb1 = bbase[b + 1];
    int m   = gb1 - gb0;
    int nb0 = b << WBITS;

    for (int i = tid; i < WNODES; i += 256) cnt[i] = 0;
    __syncthreads();
    for (int i = tid; i < m; i += 256)
        atomicAdd(&cnt[B1[gb0 + i] >> 17], 1);
    __syncthreads();
    for (int i = tid; i < WNODES; i += 256) sA[i] = cnt[i];
    __syncthreads();
    int* sp = sA; int* dp = sB;
    for (int off = 1; off < WNODES; off <<= 1) {
        for (int i = tid; i < WNODES; i += 256)
            dp[i] = sp[i] + ((i >= off) ? sp[i - off] : 0);
        __syncthreads();
        int* t = sp; sp = dp; dp = t;
    }
    for (int i = tid; i < WNODES; i += 256) {
        int ex = sp[i] - cnt[i];
        lcur[i] = ex;
        int node = nb0 + i;
        if (node < N) row_ptr[node] = gb0 + ex;
    }
    __syncthreads();
    if (m <= STG_CAP) {
        for (int i = tid; i < m; i += 256) {
            int v = B1[gb0 + i];
            int p = atomicAdd(&lcur[v >> 17], 1);
            stg[p] = v & 0x1FFFF;
        }
        __syncthreads();
        for (int i = tid; i < m; i += 256)
            col[gb0 + i] = stg[i];
    } else {               // adversarial-degree fallback (correct, uncoalesced)
        for (int i = tid; i < m; i += 256) {
            int v = B1[gb0 + i];
            int p = atomicAdd(&lcur[v >> 17], 1);
            col[gb0 + p] = v & 0x1FFFF;
        }
    }
}

// ---------------- per-layer kernels ----------------

// y[r][:] = in_row(r) @ C.T (f32) + fp16 copy y16; one thread per row.
__global__ __launch_bounds__(256) void gemm64_k(
    const float* __restrict__ in,
    const float* __restrict__ C,      // [64][64] row-major, C[d][k]
    float* __restrict__ out, unsigned* __restrict__ out16, int n)
{
    __shared__ float sCT[64 * 68];    // sCT[k*68 + d]
    int tid = threadIdx.x;
    for (int i = tid; i < 4096; i += 256) {
        int d = i >> 6, k = i & 63;
        sCT[k * 68 + d] = C[i];
    }
    __syncthreads();
    int r = blockIdx.x * 256 + tid;
    if (r >= n) return;

    float xr[64];
    const float4* xp = (const float4*)(in + (size_t)r * 64);
    #pragma unroll
    for (int k4 = 0; k4 < 16; ++k4) {
        float4 v = xp[k4];
        xr[k4 * 4 + 0] = v.x; xr[k4 * 4 + 1] = v.y;
        xr[k4 * 4 + 2] = v.z; xr[k4 * 4 + 3] = v.w;
    }

    float4* op  = (float4*)(out + (size_t)r * 64);
    uint2*  o16 = (uint2*)(out16 + (size_t)r * 32);
    for (int dg = 0; dg < 16; ++dg) {
        float a0 = 0.f, a1 = 0.f, a2 = 0.f, a3 = 0.f;
        #pragma unroll
        for (int k = 0; k < 64; ++k) {
            float4 c = *(const float4*)&sCT[k * 68 + dg * 4];
            a0 += xr[k] * c.x;
            a1 += xr[k] * c.y;
            a2 += xr[k] * c.z;
            a3 += xr[k] * c.w;
        }
        float4 o; o.x = a0; o.y = a1; o.z = a2; o.w = a3;
        op[dg] = o;
        uint2 p; p.x = pkrtz(a0, a1); p.y = pkrtz(a2, a3);
        o16[dg] = p;
    }
}

// one wave per node. fp16 rows (128B): lane t=lane&15 holds components [4t,4t+4)
// as uint2 (two packed half2); quarter q=lane>>4 handles edge k+q. col loaded
// once per 64-edge block; indices via shfl. 16-edge unroll -> 4 independent
// row loads in flight. Max via v_pk_max_f16. Subtraction uses exact f32 y_i.
// FINAL fuses the Linear(D,1)+sigmoid head.
template<bool FINAL>
__global__ __launch_bounds__(256) void gather_max_k(
    const int* __restrict__ row_ptr, const int* __restrict__ col,
    const uint2* __restrict__ y16, const float* __restrict__ y,
    float* __restrict__ agg,
    const float* __restrict__ v, const float* __restrict__ bptr,
    float* __restrict__ out, int n)
{
    int gid  = blockIdx.x * 256 + threadIdx.x;
    int node = gid >> 6;
    int lane = threadIdx.x & 63;
    int q    = lane >> 4;           // which of 4 edges in a 4-group
    int t    = lane & 15;           // component group [4t, 4t+4)
    if (node >= n) return;
    int beg = row_ptr[node], end = row_ptr[node + 1];

    unsigned c0 = PKNINF, c1 = PKNINF;
    for (int base = beg; base < end; base += 64) {
        int idx = base + lane;
        int myc = (idx < end) ? col[idx] : 0;   // one coalesced load / 64 edges
        int cnt = min(64, end - base);
        int k = 0;
        for (; k + 16 <= cnt; k += 16) {        // 4 independent row loads
            int j0 = __shfl(myc, k + q);
            int j1 = __shfl(myc, k + 4 + q);
            int j2 = __shfl(myc, k + 8 + q);
            int j3 = __shfl(myc, k + 12 + q);
            uint2 v0 = y16[(size_t)j0 * 16 + t];
            uint2 v1 = y16[(size_t)j1 * 16 + t];
            uint2 v2 = y16[(size_t)j2 * 16 + t];
            uint2 v3 = y16[(size_t)j3 * 16 + t];
            c0 = pkmax(pkmax(pkmax(c0, v0.x), pkmax(v1.x, v2.x)), v3.x);
            c1 = pkmax(pkmax(pkmax(c1, v0.y), pkmax(v1.y, v2.y)), v3.y);
        }
        for (; k + 4 <= cnt; k += 4) {
            int j = __shfl(myc, k + q);
            uint2 vv = y16[(size_t)j * 16 + t];
            c0 = pkmax(c0, vv.x);
            c1 = pkmax(c1, vv.y);
        }
        if (k < cnt) {                           // 1-3 edge tail, masked
            int kk = min(k + q, cnt - 1);
            int j  = __shfl(myc, kk);
            uint2 vv = y16[(size_t)j * 16 + t];
            bool valid = (k + q) < cnt;
            c0 = pkmax(c0, valid ? vv.x : PKNINF);
            c1 = pkmax(c1, valid ? vv.y : PKNINF);
        }
    }
    c0 = pkmax(c0, __shfl_xor(c0, 32));
    c1 = pkmax(c1, __shfl_xor(c1, 32));
    c0 = pkmax(c0, __shfl_xor(c0, 16));
    c1 = pkmax(c1, __shfl_xor(c1, 16));

    bool has = end > beg;
    if (!FINAL) {
        if (q == 0) {
            float4 yi = ((const float4*)y)[(size_t)node * 16 + t];
            float4 o;
            o.x = has ? (h2lo(c0) - yi.x) : 0.f;
            o.y = has ? (h2hi(c0) - yi.y) : 0.f;
            o.z = has ? (h2lo(c1) - yi.z) : 0.f;
            o.w = has ? (h2hi(c1) - yi.w) : 0.f;
            ((float4*)agg)[(size_t)node * 16 + t] = o;
        }
    } else {
        float s = 0.f;
        if (q == 0) {
            float4 yi = ((const float4*)y)[(size_t)node * 16 + t];
            float4 vp = ((const float4*)v)[t];
            float g0 = has ? (h2lo(c0) - yi.x) : 0.f;
            float g1 = has ? (h2hi(c0) - yi.y) : 0.f;
            float g2 = has ? (h2lo(c1) - yi.z) : 0.f;
            float g3 = has ? (h2hi(c1) - yi.w) : 0.f;
            s = g0 * vp.x + g1 * vp.y + g2 * vp.z + g3 * vp.w;
        }
        #pragma unroll
        for (int off = 8; off >= 1; off >>= 1)
            s += __shfl_xor(s, off);
        if (lane == 0)
            out[node] = 1.f / (1.f + __expf(-(s + bptr[0])));
    }
}

extern "C" void kernel_launch(void* const* d_in, const int* in_sizes, int n_in,
                              void* d_out, int out_size, void* d_ws, size_t ws_size,
                              hipStream_t stream)
{
    const float* x     = (const float*)d_in[0];
    const int*   edges = (const int*)d_in[1];   // int32 view, [2][E]
    const float* Wp    = (const float*)d_in[2];
    const float* Wt    = (const float*)d_in[3];
    const float* Wout  = (const float*)d_in[4];
    const float* bout  = (const float*)d_in[5];
    const int N = in_sizes[0] / 64;             // 100000
    const int E = in_sizes[1] / 2;              // 1600000
    const int NB = (N + WNODES - 1) >> WBITS;   // 196
    float* out = (float*)d_out;

    char* ws = (char*)d_ws;
    float* y    = (float*)ws; ws += (size_t)N * 64 * 4;
    float* agg  = (float*)ws; ws += (size_t)N * 64 * 4;
    int*   B1   = (int*)agg;                    // alias: B1 dead before agg live
    unsigned* y16 = (unsigned*)ws; ws += (size_t)N * 32 * 4;
    int* col     = (int*)ws; ws += (size_t)(E + 8) * 4;
    int* row_ptr = (int*)ws; ws += (size_t)(N + 4) * 4;
    int* bcnt    = (int*)ws; ws += MAXNB * 4;
    int* bbase   = (int*)ws; ws += (MAXNB + 4) * 4;
    int* gcur    = (int*)ws; ws += MAXNB * 4;
    float* C2 = (float*)ws; ws += 4096 * 4;
    float* C3 = (float*)ws; ws += 4096 * 4;
    float* vv = (float*)ws; ws += 64 * 4;

    const int nodeBlocks   = (N + 255) / 256;
    const int chunkBlocks  = (E + CHUNK - 1) / CHUNK;
    const int gatherBlocks = (N * 64 + 255) / 256;

    prep_k<<<3, 256, 0, stream>>>(Wp, Wt, Wout, C2, C3, vv);

    // CSR build (bucketed, write-coalesced)
    clear_int_k<<<1, 256, 0, stream>>>(bcnt, NB);
    bucket_hist_k<<<chunkBlocks, 256, 0, stream>>>(edges, bcnt, E, NB);
    bucket_scan_k<<<1, 256, 0, stream>>>(bcnt, bbase, gcur, row_ptr, NB, N, E);
    partA_k<<<chunkBlocks, 256, 0, stream>>>(edges, gcur, B1, E, NB);
    partB_k<<<NB, 256, 0, stream>>>(B1, bbase, row_ptr, col, N, NB);

    // layer 1
    gemm64_k<<<nodeBlocks, 256, 0, stream>>>(x, Wp, y, y16, N);
    gather_max_k<false><<<gatherBlocks, 256, 0, stream>>>(row_ptr, col, (const uint2*)y16, y, agg,
                                                          nullptr, nullptr, nullptr, N);
    // layer 2
    gemm64_k<<<nodeBlocks, 256, 0, stream>>>(agg, C2, y, y16, N);
    gather_max_k<false><<<gatherBlocks, 256, 0, stream>>>(row_ptr, col, (const uint2*)y16, y, agg,
                                                          nullptr, nullptr, nullptr, N);
    // layer 3
    gemm64_k<<<nodeBlocks, 256, 0, stream>>>(agg, C3, y, y16, N);
    gather_max_k<true><<<gatherBlocks, 256, 0, stream>>>(row_ptr, col, (const uint2*)y16, y, nullptr,
                                                         vv, bout, out, N);
}

// Round 8
// 248.031 us; speedup vs baseline: 1.4577x; 1.2437x over previous
//
#include <hip/hip_runtime.h>
#include <math.h>

// ---------------------------------------------------------------------------
// PointSampler / DevConv, CSR-gather + MFMA fp16 GEMM.
//   CSR build: bucket_hist -> bucket_scan -> partA -> partB (write-coalesced)
//   per layer l: y = h @ Cl.T via mfma_f32_16x16x32_f16 (f32 accum),
//                outputs y32 (f32, for exact subtraction) + y16 (fp16 gather op)
//                gather: agg16[i] = fp16( deg>0 ? max_j y16[j] - y32[i] : 0 )
//   head (fused into 3rd gather): out[i] = sigmoid( agg3[i] . v + b )
// ---------------------------------------------------------------------------

#define WBITS 9
#define WNODES 512            // nodes per bucket
#define MAXNB 256             // max buckets (requires N <= 131072, src < 2^17)
#define CHUNK 8192            // edges per partA/hist block
#define STG_CAP 12288         // partB LDS staging entries (48 KB)

#define PKNINF 0xFC00FC00u    // packed fp16 (-inf, -inf)

typedef __fp16 h2v __attribute__((ext_vector_type(2)));
typedef _Float16 f16x8 __attribute__((ext_vector_type(8)));
typedef float f32x4 __attribute__((ext_vector_type(4)));

__device__ __forceinline__ unsigned pkmax(unsigned a, unsigned b) {
    unsigned r;
    asm("v_pk_max_f16 %0, %1, %2" : "=v"(r) : "v"(a), "v"(b));
    return r;
}
__device__ __forceinline__ unsigned pkrtz(float a, float b) {
    h2v r = __builtin_amdgcn_cvt_pkrtz(a, b);
    return *reinterpret_cast<unsigned*>(&r);
}
__device__ __forceinline__ float h2lo(unsigned u) {
    h2v h = *reinterpret_cast<h2v*>(&u);
    return (float)h.x;
}
__device__ __forceinline__ float h2hi(unsigned u) {
    h2v h = *reinterpret_cast<h2v*>(&u);
    return (float)h.y;
}

// block 0: Wh1 = fp16(Wp[1]@Wt[0]); block 1: Wh2 = fp16(Wp[2]@Wt[1]);
// block 2: vv = Wout@Wt[2] (f32) and Wh0 = fp16(Wp[0])
__global__ __launch_bounds__(256) void prep_k(
    const float* __restrict__ Wp, const float* __restrict__ Wt,
    const float* __restrict__ Wout,
    __fp16* __restrict__ Wh, float* __restrict__ vout)
{
    __shared__ float A[4096];
    __shared__ float B[4096];
    int tid = threadIdx.x;
    int b = blockIdx.x;
    if (b < 2) {
        const float* Ap = Wp + (size_t)(b + 1) * 4096;
        const float* Bp = Wt + (size_t)b * 4096;
        for (int i = tid; i < 4096; i += 256) { A[i] = Ap[i]; B[i] = Bp[i]; }
        __syncthreads();
        __fp16* C = Wh + (size_t)(b + 1) * 4096;
        for (int i = tid; i < 4096; i += 256) {
            int d = i >> 6, k = i & 63;
            float s = 0.f;
            #pragma unroll
            for (int m = 0; m < 64; ++m) s += A[d * 64 + m] * B[m * 64 + k];
            C[i] = (__fp16)s;
        }
    } else {
        for (int i = tid; i < 4096; i += 256) {
            A[i] = Wt[2 * 4096 + i];
            Wh[i] = (__fp16)Wp[i];
        }
        if (tid < 64) B[tid] = Wout[tid];
        __syncthreads();
        if (tid < 64) {
            float s = 0.f;
            #pragma unroll
            for (int m = 0; m < 64; ++m) s += B[m] * A[m * 64 + tid];
            vout[tid] = s;
        }
    }
}

__global__ __launch_bounds__(256) void clear_int_k(int* __restrict__ p, int n)
{
    int i = blockIdx.x * 256 + threadIdx.x;
    if (i < n) p[i] = 0;
}

// per-chunk LDS histogram of dst buckets -> global bucket counts
__global__ __launch_bounds__(256) void bucket_hist_k(
    const int* __restrict__ eidx, int* __restrict__ bcnt, int E, int NB)
{
    __shared__ int h[MAXNB];
    int tid = threadIdx.x;
    for (int i = tid; i < NB; i += 256) h[i] = 0;
    __syncthreads();
    int start = blockIdx.x * CHUNK;
    int end = min(E, start + CHUNK);
    for (int e = start + tid; e < end; e += 256)
        atomicAdd(&h[eidx[E + e] >> WBITS], 1);
    __syncthreads();
    for (int i = tid; i < NB; i += 256)
        if (h[i]) atomicAdd(&bcnt[i], h[i]);
}

// 1-block scan of bucket counts -> bbase (exclusive), init gcur, row_ptr[N]=E
__global__ __launch_bounds__(256) void bucket_scan_k(
    const int* __restrict__ bcnt, int* __restrict__ bbase,
    int* __restrict__ gcur, int* __restrict__ row_ptr, int NB, int N, int E)
{
    __shared__ int sA[MAXNB], sB[MAXNB];
    int tid = threadIdx.x;
    int v0 = (tid < NB) ? bcnt[tid] : 0;
    sA[tid] = v0;
    __syncthreads();
    int* sp = sA; int* dp = sB;
    for (int off = 1; off < MAXNB; off <<= 1) {
        dp[tid] = sp[tid] + ((tid >= off) ? sp[tid - off] : 0);
        __syncthreads();
        int* t = sp; sp = dp; dp = t;
    }
    if (tid < NB) {
        int ex = sp[tid] - v0;
        bbase[tid] = ex;
        gcur[tid]  = ex;
    }
    if (tid == 0) {
        bbase[NB]  = E;
        row_ptr[N] = E;
    }
}

// partition edges into bucket-major order (packed src | dstLow<<17)
__global__ __launch_bounds__(256) void partA_k(
    const int* __restrict__ eidx, int* __restrict__ gcur,
    int* __restrict__ B1, int E, int NB)
{
    __shared__ int hist[MAXNB];
    __shared__ int lofs[MAXNB];
    __shared__ int lcur[MAXNB];
    __shared__ int gofs[MAXNB];
    __shared__ int sA[MAXNB], sB[MAXNB];
    __shared__ int stg_val[CHUNK];
    __shared__ int stg_pos[CHUNK];
    int tid = threadIdx.x;
    int start = blockIdx.x * CHUNK;
    int cnt = min(E - start, CHUNK);
    if (cnt <= 0) return;

    for (int i = tid; i < NB; i += 256) hist[i] = 0;
    __syncthreads();

    int es[CHUNK / 256], ed[CHUNK / 256];
    #pragma unroll
    for (int i = 0; i < CHUNK / 256; ++i) {
        int li = i * 256 + tid;
        if (li < cnt) {
            es[i] = eidx[start + li];
            ed[i] = eidx[E + start + li];
            atomicAdd(&hist[ed[i] >> WBITS], 1);
        }
    }
    __syncthreads();
    sA[tid] = (tid < NB) ? hist[tid] : 0;
    __syncthreads();
    int* sp = sA; int* dp = sB;
    for (int off = 1; off < MAXNB; off <<= 1) {
        dp[tid] = sp[tid] + ((tid >= off) ? sp[tid - off] : 0);
        __syncthreads();
        int* t = sp; sp = dp; dp = t;
    }
    if (tid < NB) {
        int c  = hist[tid];
        int ex = sp[tid] - c;
        lofs[tid] = ex;
        lcur[tid] = ex;
        gofs[tid] = c ? atomicAdd(&gcur[tid], c) : 0;
    }
    __syncthreads();
    #pragma unroll
    for (int i = 0; i < CHUNK / 256; ++i) {
        int li = i * 256 + tid;
        if (li < cnt) {
            int b = ed[i] >> WBITS;
            int p = atomicAdd(&lcur[b], 1);
            stg_val[p] = es[i] | ((ed[i] & (WNODES - 1)) << 17);
            stg_pos[p] = gofs[b] + (p - lofs[b]);
        }
    }
    __syncthreads();
    for (int i = tid; i < cnt; i += 256)
        B1[stg_pos[i]] = stg_val[i];
}

// per-bucket: degree count -> scan -> row_ptr; LDS-staged coalesced col scatter
__global__ __launch_bounds__(256) void partB_k(
    const int* __restrict__ B1, const int* __restrict__ bbase,
    int* __restrict__ row_ptr, int* __restrict__ col, int N, int NB)
{
    __shared__ int cnt[WNODES];
    __shared__ int lcur[WNODES];
    __shared__ int sA[WNODES], sB[WNODES];
    __shared__ int stg[STG_CAP];
    int b   = blockIdx.x;
    int tid = threadIdx.x;
    int gb0 = bbase[b], gb1 = bbase[b + 1];
    int m   = gb1 - gb0;
    int nb0 = b << WBITS;

    for (int i = tid; i < WNODES; i += 256) cnt[i] = 0;
    __syncthreads();
    for (int i = tid; i < m; i += 256)
        atomicAdd(&cnt[B1[gb0 + i] >> 17], 1);
    __syncthreads();
    for (int i = tid; i < WNODES; i += 256) sA[i] = cnt[i];
    __syncthreads();
    int* sp = sA; int* dp = sB;
    for (int off = 1; off < WNODES; off <<= 1) {
        for (int i = tid; i < WNODES; i += 256)
            dp[i] = sp[i] + ((i >= off) ? sp[i - off] : 0);
        __syncthreads();
        int* t = sp; sp = dp; dp = t;
    }
    for (int i = tid; i < WNODES; i += 256) {
        int ex = sp[i] - cnt[i];
        lcur[i] = ex;
        int node = nb0 + i;
        if (node < N) row_ptr[node] = gb0 + ex;
    }
    __syncthreads();
    if (m <= STG_CAP) {
        for (int i = tid; i < m; i += 256) {
            int v = B1[gb0 + i];
            int p = atomicAdd(&lcur[v >> 17], 1);
            stg[p] = v & 0x1FFFF;
        }
        __syncthreads();
        for (int i = tid; i < m; i += 256)
            col[gb0 + i] = stg[i];
    } else {               // adversarial-degree fallback (correct, uncoalesced)
        for (int i = tid; i < m; i += 256) {
            int v = B1[gb0 + i];
            int p = atomicAdd(&lcur[v >> 17], 1);
            col[gb0 + p] = v & 0x1FFFF;
        }
    }
}

// ---------------- per-layer kernels ----------------

// MFMA GEMM: y[r][d] = sum_k in[r][k] * W[d][k], W fp16 row-major.
// One wave per 16-row tile; A-frag = weights (preloaded, 8 frags), B-frag =
// input rows (16B contiguous per lane). D: lane holds 4 consecutive d for
// node r = r0 + (lane&15). Outputs y32 (f32) + y16 (fp16).
// F32IN: input is f32 (x), converted to fp16 in-register.
template<bool F32IN>
__global__ __launch_bounds__(256) void gemm_mfma_k(
    const void* __restrict__ in, const __fp16* __restrict__ W,
    float* __restrict__ y32, unsigned short* __restrict__ y16, int n)
{
    int lane = threadIdx.x & 63;
    int wid  = threadIdx.x >> 6;
    int rt   = blockIdx.x * 4 + wid;
    int r0   = rt * 16;
    if (r0 >= n) return;

    int l15 = lane & 15;
    int ko  = (lane >> 4) * 8;       // k-offset within 32-wide frag

    // preload A-frags: weights [dtile][kfrag]
    f16x8 af[4][2];
    #pragma unroll
    for (int dt = 0; dt < 4; ++dt)
        #pragma unroll
        for (int kf = 0; kf < 2; ++kf)
            af[dt][kf] = *(const f16x8*)(W + (size_t)(dt * 16 + l15) * 64 + ko + kf * 32);

    // B-frags: input rows
    f16x8 bf[2];
    if (F32IN) {
        const float* xin = (const float*)in;
        #pragma unroll
        for (int kf = 0; kf < 2; ++kf) {
            const float4* p = (const float4*)(xin + (size_t)(r0 + l15) * 64 + ko + kf * 32);
            float4 a = p[0], b = p[1];
            union { uint4 u; f16x8 h; } cv;
            cv.u.x = pkrtz(a.x, a.y); cv.u.y = pkrtz(a.z, a.w);
            cv.u.z = pkrtz(b.x, b.y); cv.u.w = pkrtz(b.z, b.w);
            bf[kf] = cv.h;
        }
    } else {
        const unsigned short* hin = (const unsigned short*)in;
        #pragma unroll
        for (int kf = 0; kf < 2; ++kf)
            bf[kf] = *(const f16x8*)(hin + (size_t)(r0 + l15) * 64 + ko + kf * 32);
    }

    int r = r0 + l15;
    int d4 = (lane >> 4) * 4;
    #pragma unroll
    for (int dt = 0; dt < 4; ++dt) {
        f32x4 acc = {0.f, 0.f, 0.f, 0.f};
        acc = __builtin_amdgcn_mfma_f32_16x16x32_f16(af[dt][0], bf[0], acc, 0, 0, 0);
        acc = __builtin_amdgcn_mfma_f32_16x16x32_f16(af[dt][1], bf[1], acc, 0, 0, 0);
        int d = dt * 16 + d4;
        float4 o; o.x = acc[0]; o.y = acc[1]; o.z = acc[2]; o.w = acc[3];
        *(float4*)(y32 + (size_t)r * 64 + d) = o;
        uint2 p; p.x = pkrtz(acc[0], acc[1]); p.y = pkrtz(acc[2], acc[3]);
        *(uint2*)(y16 + (size_t)r * 64 + d) = p;
    }
}

// one wave per node. fp16 rows (128B): lane t=lane&15 holds components [4t,4t+4)
// as uint2 (two packed half2); quarter q=lane>>4 handles edge k+q. col loaded
// once per 64-edge block; indices via shfl. 16-edge unroll -> 4 independent
// row loads in flight. Max via v_pk_max_f16. Subtraction uses exact f32 y_i.
// Non-FINAL writes fp16 agg16 (next GEMM's B operand). FINAL fuses the head.
template<bool FINAL>
__global__ __launch_bounds__(256) void gather_max_k(
    const int* __restrict__ row_ptr, const int* __restrict__ col,
    const uint2* __restrict__ y16, const float* __restrict__ y,
    uint2* __restrict__ agg16,
    const float* __restrict__ v, const float* __restrict__ bptr,
    float* __restrict__ out, int n)
{
    int gid  = blockIdx.x * 256 + threadIdx.x;
    int node = gid >> 6;
    int lane = threadIdx.x & 63;
    int q    = lane >> 4;           // which of 4 edges in a 4-group
    int t    = lane & 15;           // component group [4t, 4t+4)
    if (node >= n) return;
    int beg = row_ptr[node], end = row_ptr[node + 1];

    unsigned c0 = PKNINF, c1 = PKNINF;
    for (int base = beg; base < end; base += 64) {
        int idx = base + lane;
        int myc = (idx < end) ? col[idx] : 0;   // one coalesced load / 64 edges
        int cnt = min(64, end - base);
        int k = 0;
        for (; k + 16 <= cnt; k += 16) {        // 4 independent row loads
            int j0 = __shfl(myc, k + q);
            int j1 = __shfl(myc, k + 4 + q);
            int j2 = __shfl(myc, k + 8 + q);
            int j3 = __shfl(myc, k + 12 + q);
            uint2 v0 = y16[(size_t)j0 * 16 + t];
            uint2 v1 = y16[(size_t)j1 * 16 + t];
            uint2 v2 = y16[(size_t)j2 * 16 + t];
            uint2 v3 = y16[(size_t)j3 * 16 + t];
            c0 = pkmax(pkmax(pkmax(c0, v0.x), pkmax(v1.x, v2.x)), v3.x);
            c1 = pkmax(pkmax(pkmax(c1, v0.y), pkmax(v1.y, v2.y)), v3.y);
        }
        for (; k + 4 <= cnt; k += 4) {
            int j = __shfl(myc, k + q);
            uint2 vv = y16[(size_t)j * 16 + t];
            c0 = pkmax(c0, vv.x);
            c1 = pkmax(c1, vv.y);
        }
        if (k < cnt) {                           // 1-3 edge tail, masked
            int kk = min(k + q, cnt - 1);
            int j  = __shfl(myc, kk);
            uint2 vv = y16[(size_t)j * 16 + t];
            bool valid = (k + q) < cnt;
            c0 = pkmax(c0, valid ? vv.x : PKNINF);
            c1 = pkmax(c1, valid ? vv.y : PKNINF);
        }
    }
    c0 = pkmax(c0, __shfl_xor(c0, 32));
    c1 = pkmax(c1, __shfl_xor(c1, 32));
    c0 = pkmax(c0, __shfl_xor(c0, 16));
    c1 = pkmax(c1, __shfl_xor(c1, 16));

    bool has = end > beg;
    if (!FINAL) {
        if (q == 0) {
            float4 yi = ((const float4*)y)[(size_t)node * 16 + t];
            float g0 = has ? (h2lo(c0) - yi.x) : 0.f;
            float g1 = has ? (h2hi(c0) - yi.y) : 0.f;
            float g2 = has ? (h2lo(c1) - yi.z) : 0.f;
            float g3 = has ? (h2hi(c1) - yi.w) : 0.f;
            uint2 p; p.x = pkrtz(g0, g1); p.y = pkrtz(g2, g3);
            agg16[(size_t)node * 16 + t] = p;
        }
    } else {
        float s = 0.f;
        if (q == 0) {
            float4 yi = ((const float4*)y)[(size_t)node * 16 + t];
            float4 vp = ((const float4*)v)[t];
            float g0 = has ? (h2lo(c0) - yi.x) : 0.f;
            float g1 = has ? (h2hi(c0) - yi.y) : 0.f;
            float g2 = has ? (h2lo(c1) - yi.z) : 0.f;
            float g3 = has ? (h2hi(c1) - yi.w) : 0.f;
            s = g0 * vp.x + g1 * vp.y + g2 * vp.z + g3 * vp.w;
        }
        #pragma unroll
        for (int off = 8; off >= 1; off >>= 1)
            s += __shfl_xor(s, off);
        if (lane == 0)
            out[node] = 1.f / (1.f + __expf(-(s + bptr[0])));
    }
}

extern "C" void kernel_launch(void* const* d_in, const int* in_sizes, int n_in,
                              void* d_out, int out_size, void* d_ws, size_t ws_size,
                              hipStream_t stream)
{
    const float* x     = (const float*)d_in[0];
    const int*   edges = (const int*)d_in[1];   // int32 view, [2][E]
    const float* Wp    = (const float*)d_in[2];
    const float* Wt    = (const float*)d_in[3];
    const float* Wout  = (const float*)d_in[4];
    const float* bout  = (const float*)d_in[5];
    const int N = in_sizes[0] / 64;             // 100000
    const int E = in_sizes[1] / 2;              // 1600000
    const int NB = (N + WNODES - 1) >> WBITS;   // 196
    float* out = (float*)d_out;

    char* ws = (char*)d_ws;
    float* y32 = (float*)ws; ws += (size_t)N * 64 * 4;
    int*   B1  = (int*)y32;                     // alias: B1 dead before y32 live
    unsigned short* y16   = (unsigned short*)ws; ws += (size_t)N * 64 * 2;
    unsigned short* agg16 = (unsigned short*)ws; ws += (size_t)N * 64 * 2;
    int* col     = (int*)ws; ws += (size_t)(E + 8) * 4;
    int* row_ptr = (int*)ws; ws += (size_t)(N + 4) * 4;
    int* bcnt    = (int*)ws; ws += MAXNB * 4;
    int* bbase   = (int*)ws; ws += (MAXNB + 4) * 4;
    int* gcur    = (int*)ws; ws += MAXNB * 4;
    __fp16* Wh = (__fp16*)ws; ws += 3 * 4096 * 2;
    float*  vv = (float*)ws;  ws += 64 * 4;

    const int chunkBlocks  = (E + CHUNK - 1) / CHUNK;
    const int gatherBlocks = (N * 64 + 255) / 256;
    const int gemmBlocks   = ((N + 15) / 16 + 3) / 4;

    prep_k<<<3, 256, 0, stream>>>(Wp, Wt, Wout, Wh, vv);

    // CSR build (bucketed, write-coalesced)
    clear_int_k<<<1, 256, 0, stream>>>(bcnt, NB);
    bucket_hist_k<<<chunkBlocks, 256, 0, stream>>>(edges, bcnt, E, NB);
    bucket_scan_k<<<1, 256, 0, stream>>>(bcnt, bbase, gcur, row_ptr, NB, N, E);
    partA_k<<<chunkBlocks, 256, 0, stream>>>(edges, gcur, B1, E, NB);
    partB_k<<<NB, 256, 0, stream>>>(B1, bbase, row_ptr, col, N, NB);

    // layer 1
    gemm_mfma_k<true><<<gemmBlocks, 256, 0, stream>>>(x, Wh, y32, y16, N);
    gather_max_k<false><<<gatherBlocks, 256, 0, stream>>>(row_ptr, col, (const uint2*)y16, y32,
                                                          (uint2*)agg16, nullptr, nullptr, nullptr, N);
    // layer 2
    gemm_mfma_k<false><<<gemmBlocks, 256, 0, stream>>>(agg16, Wh + 4096, y32, y16, N);
    gather_max_k<false><<<gatherBlocks, 256, 0, stream>>>(row_ptr, col, (const uint2*)y16, y32,
                                                          (uint2*)agg16, nullptr, nullptr, nullptr, N);
    // layer 3
    gemm_mfma_k<false><<<gemmBlocks, 256, 0, stream>>>(agg16, Wh + 8192, y32, y16, N);
    gather_max_k<true><<<gatherBlocks, 256, 0, stream>>>(row_ptr, col, (const uint2*)y16, y32,
                                                         nullptr, vv, bout, out, N);
}

// Round 9
// 205.191 us; speedup vs baseline: 1.7620x; 1.2088x over previous
//
#include <hip/hip_runtime.h>
#include <math.h>

// ---------------------------------------------------------------------------
// PointSampler / DevConv: CSR-gather (4 nodes/wave, clamp-padded, swizzle
// broadcast) fused with the next layer's MFMA fp16 GEMM.
//   CSR build: bucket_hist -> bucket_scan -> partA -> partB (write-coalesced)
//   layer 1 GEMM standalone (x f32 -> y32,y16A)
//   fused l:   gather(y16,y32) -> LDS agg tile -> MFMA -> y32,y16other
//   final:     gather + Linear(D,1)+sigmoid head
// ---------------------------------------------------------------------------

#define WBITS 9
#define WNODES 512            // nodes per bucket
#define MAXNB 256             // max buckets (requires N <= 131072, src < 2^17)
#define CHUNK 8192            // edges per partA/hist block
#define STG_CAP 12288         // partB LDS staging entries (48 KB)

#define PKNINF 0xFC00FC00u    // packed fp16 (-inf, -inf)

typedef __fp16 h2v __attribute__((ext_vector_type(2)));
typedef _Float16 f16x8 __attribute__((ext_vector_type(8)));
typedef float f32x4 __attribute__((ext_vector_type(4)));

__device__ __forceinline__ unsigned pkmax(unsigned a, unsigned b) {
    unsigned r;
    asm("v_pk_max_f16 %0, %1, %2" : "=v"(r) : "v"(a), "v"(b));
    return r;
}
__device__ __forceinline__ unsigned pkrtz(float a, float b) {
    h2v r = __builtin_amdgcn_cvt_pkrtz(a, b);
    return *reinterpret_cast<unsigned*>(&r);
}
__device__ __forceinline__ float h2lo(unsigned u) {
    h2v h = *reinterpret_cast<h2v*>(&u);
    return (float)h.x;
}
__device__ __forceinline__ float h2hi(unsigned u) {
    h2v h = *reinterpret_cast<h2v*>(&u);
    return (float)h.y;
}

// 8 edges: broadcast col idx from quarter-lane K0+k, load 8B of fp16 row, pkmax
#define G8(K0) do { \
    int j0 = __builtin_amdgcn_ds_swizzle(myc, (((K0)+0)<<5)|0x10); \
    int j1 = __builtin_amdgcn_ds_swizzle(myc, (((K0)+1)<<5)|0x10); \
    int j2 = __builtin_amdgcn_ds_swizzle(myc, (((K0)+2)<<5)|0x10); \
    int j3 = __builtin_amdgcn_ds_swizzle(myc, (((K0)+3)<<5)|0x10); \
    int j4 = __builtin_amdgcn_ds_swizzle(myc, (((K0)+4)<<5)|0x10); \
    int j5 = __builtin_amdgcn_ds_swizzle(myc, (((K0)+5)<<5)|0x10); \
    int j6 = __builtin_amdgcn_ds_swizzle(myc, (((K0)+6)<<5)|0x10); \
    int j7 = __builtin_amdgcn_ds_swizzle(myc, (((K0)+7)<<5)|0x10); \
    uint2 w0 = y16[(size_t)j0 * 16 + t]; \
    uint2 w1 = y16[(size_t)j1 * 16 + t]; \
    uint2 w2 = y16[(size_t)j2 * 16 + t]; \
    uint2 w3 = y16[(size_t)j3 * 16 + t]; \
    uint2 w4 = y16[(size_t)j4 * 16 + t]; \
    uint2 w5 = y16[(size_t)j5 * 16 + t]; \
    uint2 w6 = y16[(size_t)j6 * 16 + t]; \
    uint2 w7 = y16[(size_t)j7 * 16 + t]; \
    c0 = pkmax(c0, pkmax(pkmax(pkmax(w0.x, w1.x), pkmax(w2.x, w3.x)), \
                         pkmax(pkmax(w4.x, w5.x), pkmax(w6.x, w7.x)))); \
    c1 = pkmax(c1, pkmax(pkmax(pkmax(w0.y, w1.y), pkmax(w2.y, w3.y)), \
                         pkmax(pkmax(w4.y, w5.y), pkmax(w6.y, w7.y)))); \
} while (0)

// block 0: Wh1 = fp16(Wp[1]@Wt[0]); block 1: Wh2 = fp16(Wp[2]@Wt[1]);
// block 2: vv = Wout@Wt[2] (f32) and Wh0 = fp16(Wp[0])
__global__ __launch_bounds__(256) void prep_k(
    const float* __restrict__ Wp, const float* __restrict__ Wt,
    const float* __restrict__ Wout,
    __fp16* __restrict__ Wh, float* __restrict__ vout)
{
    __shared__ float A[4096];
    __shared__ float B[4096];
    int tid = threadIdx.x;
    int b = blockIdx.x;
    if (b < 2) {
        const float* Ap = Wp + (size_t)(b + 1) * 4096;
        const float* Bp = Wt + (size_t)b * 4096;
        for (int i = tid; i < 4096; i += 256) { A[i] = Ap[i]; B[i] = Bp[i]; }
        __syncthreads();
        __fp16* C = Wh + (size_t)(b + 1) * 4096;
        for (int i = tid; i < 4096; i += 256) {
            int d = i >> 6, k = i & 63;
            float s = 0.f;
            #pragma unroll
            for (int m = 0; m < 64; ++m) s += A[d * 64 + m] * B[m * 64 + k];
            C[i] = (__fp16)s;
        }
    } else {
        for (int i = tid; i < 4096; i += 256) {
            A[i] = Wt[2 * 4096 + i];
            Wh[i] = (__fp16)Wp[i];
        }
        if (tid < 64) B[tid] = Wout[tid];
        __syncthreads();
        if (tid < 64) {
            float s = 0.f;
            #pragma unroll
            for (int m = 0; m < 64; ++m) s += B[m] * A[m * 64 + tid];
            vout[tid] = s;
        }
    }
}

__global__ __launch_bounds__(256) void clear_int_k(int* __restrict__ p, int n)
{
    int i = blockIdx.x * 256 + threadIdx.x;
    if (i < n) p[i] = 0;
}

// per-chunk LDS histogram of dst buckets -> global bucket counts
__global__ __launch_bounds__(256) void bucket_hist_k(
    const int* __restrict__ eidx, int* __restrict__ bcnt, int E, int NB)
{
    __shared__ int h[MAXNB];
    int tid = threadIdx.x;
    for (int i = tid; i < NB; i += 256) h[i] = 0;
    __syncthreads();
    int start = blockIdx.x * CHUNK;
    int end = min(E, start + CHUNK);
    for (int e = start + tid; e < end; e += 256)
        atomicAdd(&h[eidx[E + e] >> WBITS], 1);
    __syncthreads();
    for (int i = tid; i < NB; i += 256)
        if (h[i]) atomicAdd(&bcnt[i], h[i]);
}

// 1-block scan of bucket counts -> bbase (exclusive), init gcur, row_ptr[N]=E
__global__ __launch_bounds__(256) void bucket_scan_k(
    const int* __restrict__ bcnt, int* __restrict__ bbase,
    int* __restrict__ gcur, int* __restrict__ row_ptr, int NB, int N, int E)
{
    __shared__ int sA[MAXNB], sB[MAXNB];
    int tid = threadIdx.x;
    int v0 = (tid < NB) ? bcnt[tid] : 0;
    sA[tid] = v0;
    __syncthreads();
    int* sp = sA; int* dp = sB;
    for (int off = 1; off < MAXNB; off <<= 1) {
        dp[tid] = sp[tid] + ((tid >= off) ? sp[tid - off] : 0);
        __syncthreads();
        int* t = sp; sp = dp; dp = t;
    }
    if (tid < NB) {
        int ex = sp[tid] - v0;
        bbase[tid] = ex;
        gcur[tid]  = ex;
    }
    if (tid == 0) {
        bbase[NB]  = E;
        row_ptr[N] = E;
    }
}

// partition edges into bucket-major order (packed src | dstLow<<17)
__global__ __launch_bounds__(256) void partA_k(
    const int* __restrict__ eidx, int* __restrict__ gcur,
    int* __restrict__ B1, int E, int NB)
{
    __shared__ int hist[MAXNB];
    __shared__ int lofs[MAXNB];
    __shared__ int lcur[MAXNB];
    __shared__ int gofs[MAXNB];
    __shared__ int sA[MAXNB], sB[MAXNB];
    __shared__ int stg_val[CHUNK];
    __shared__ int stg_pos[CHUNK];
    int tid = threadIdx.x;
    int start = blockIdx.x * CHUNK;
    int cnt = min(E - start, CHUNK);
    if (cnt <= 0) return;

    for (int i = tid; i < NB; i += 256) hist[i] = 0;
    __syncthreads();

    int es[CHUNK / 256], ed[CHUNK / 256];
    #pragma unroll
    for (int i = 0; i < CHUNK / 256; ++i) {
        int li = i * 256 + tid;
        if (li < cnt) {
            es[i] = eidx[start + li];
            ed[i] = eidx[E + start + li];
            atomicAdd(&hist[ed[i] >> WBITS], 1);
        }
    }
    __syncthreads();
    sA[tid] = (tid < NB) ? hist[tid] : 0;
    __syncthreads();
    int* sp = sA; int* dp = sB;
    for (int off = 1; off < MAXNB; off <<= 1) {
        dp[tid] = sp[tid] + ((tid >= off) ? sp[tid - off] : 0);
        __syncthreads();
        int* t = sp; sp = dp; dp = t;
    }
    if (tid < NB) {
        int c  = hist[tid];
        int ex = sp[tid] - c;
        lofs[tid] = ex;
        lcur[tid] = ex;
        gofs[tid] = c ? atomicAdd(&gcur[tid], c) : 0;
    }
    __syncthreads();
    #pragma unroll
    for (int i = 0; i < CHUNK / 256; ++i) {
        int li = i * 256 + tid;
        if (li < cnt) {
            int b = ed[i] >> WBITS;
            int p = atomicAdd(&lcur[b], 1);
            stg_val[p] = es[i] | ((ed[i] & (WNODES - 1)) << 17);
            stg_pos[p] = gofs[b] + (p - lofs[b]);
        }
    }
    __syncthreads();
    for (int i = tid; i < cnt; i += 256)
        B1[stg_pos[i]] = stg_val[i];
}

// per-bucket: degree count -> scan -> row_ptr; LDS-staged coalesced col scatter
__global__ __launch_bounds__(256) void partB_k(
    const int* __restrict__ B1, const int* __restrict__ bbase,
    int* __restrict__ row_ptr, int* __restrict__ col, int N, int NB)
{
    __shared__ int cnt[WNODES];
    __shared__ int lcur[WNODES];
    __shared__ int sA[WNODES], sB[WNODES];
    __shared__ int stg[STG_CAP];
    int b   = blockIdx.x;
    int tid = threadIdx.x;
    int gb0 = bbase[b], gb1 = bbase[b + 1];
    int m   = gb1 - gb0;
    int nb0 = b << WBITS;

    for (int i = tid; i < WNODES; i += 256) cnt[i] = 0;
    __syncthreads();
    for (int i = tid; i < m; i += 256)
        atomicAdd(&cnt[B1[gb0 + i] >> 17], 1);
    __syncthreads();
    for (int i = tid; i < WNODES; i += 256) sA[i] = cnt[i];
    __syncthreads();
    int* sp = sA; int* dp = sB;
    for (int off = 1; off < WNODES; off <<= 1) {
        for (int i = tid; i < WNODES; i += 256)
            dp[i] = sp[i] + ((i >= off) ? sp[i - off] : 0);
        __syncthreads();
        int* t = sp; sp = dp; dp = t;
    }
    for (int i = tid; i < WNODES; i += 256) {
        int ex = sp[i] - cnt[i];
        lcur[i] = ex;
        int node = nb0 + i;
        if (node < N) row_ptr[node] = gb0 + ex;
    }
    __syncthreads();
    if (m <= STG_CAP) {
        for (int i = tid; i < m; i += 256) {
            int v = B1[gb0 + i];
            int p = atomicAdd(&lcur[v >> 17], 1);
            stg[p] = v & 0x1FFFF;
        }
        __syncthreads();
        for (int i = tid; i < m; i += 256)
            col[gb0 + i] = stg[i];
    } else {               // adversarial-degree fallback (correct, uncoalesced)
        for (int i = tid; i < m; i += 256) {
            int v = B1[gb0 + i];
            int p = atomicAdd(&lcur[v >> 17], 1);
            col[gb0 + p] = v & 0x1FFFF;
        }
    }
}

// ---------------- per-layer kernels ----------------

// MFMA GEMM (layer 1): y[r][d] = sum_k x[r][k] * W[d][k], W fp16 row-major.
__global__ __launch_bounds__(256) void gemm_mfma_k(
    const float* __restrict__ in, const __fp16* __restrict__ W,
    float* __restrict__ y32, unsigned short* __restrict__ y16, int n)
{
    int lane = threadIdx.x & 63;
    int wid  = threadIdx.x >> 6;
    int rt   = blockIdx.x * 4 + wid;
    int r0   = rt * 16;
    if (r0 >= n) return;

    int l15 = lane & 15;
    int ko  = (lane >> 4) * 8;

    f16x8 af[4][2];
    #pragma unroll
    for (int dt = 0; dt < 4; ++dt)
        #pragma unroll
        for (int kf = 0; kf < 2; ++kf)
            af[dt][kf] = *(const f16x8*)(W + (size_t)(dt * 16 + l15) * 64 + ko + kf * 32);

    f16x8 bf[2];
    #pragma unroll
    for (int kf = 0; kf < 2; ++kf) {
        const float4* p = (const float4*)(in + (size_t)(r0 + l15) * 64 + ko + kf * 32);
        float4 a = p[0], b = p[1];
        union { uint4 u; f16x8 h; } cv;
        cv.u.x = pkrtz(a.x, a.y); cv.u.y = pkrtz(a.z, a.w);
        cv.u.z = pkrtz(b.x, b.y); cv.u.w = pkrtz(b.z, b.w);
        bf[kf] = cv.h;
    }

    int r = r0 + l15;
    int d4 = (lane >> 4) * 4;
    #pragma unroll
    for (int dt = 0; dt < 4; ++dt) {
        f32x4 acc = {0.f, 0.f, 0.f, 0.f};
        acc = __builtin_amdgcn_mfma_f32_16x16x32_f16(af[dt][0], bf[0], acc, 0, 0, 0);
        acc = __builtin_amdgcn_mfma_f32_16x16x32_f16(af[dt][1], bf[1], acc, 0, 0, 0);
        int d = dt * 16 + d4;
        if (r < n) {
            float4 o; o.x = acc[0]; o.y = acc[1]; o.z = acc[2]; o.w = acc[3];
            *(float4*)(y32 + (size_t)r * 64 + d) = o;
            uint2 p; p.x = pkrtz(acc[0], acc[1]); p.y = pkrtz(acc[2], acc[3]);
            *(uint2*)(y16 + (size_t)r * 64 + d) = p;
        }
    }
}

// Fused gather (+ next-layer GEMM | head).
// Wave = 4 nodes/pass x 4 passes = 16 nodes; quarter q owns a node, lane t
// holds comps [4t,4t+4) as uint2. Edges clamp-padded to multiple of 8 (dup of
// last neighbor; cache-hot). ds_swizzle broadcasts col indices (MLP 8).
// HEAD=false: agg -> LDS tile -> per-wave 16-row MFMA -> y32o/y16o.
// HEAD=true:  agg . v + b -> sigmoid -> out.
template<bool HEAD>
__global__ __launch_bounds__(256) void gather_fused_k(
    const int* __restrict__ rp, const int* __restrict__ col,
    const uint2* __restrict__ y16, const float* y32,
    const __fp16* __restrict__ W,
    float* y32o, unsigned short* __restrict__ y16o,
    const float* __restrict__ vv, const float* __restrict__ bptr,
    float* __restrict__ out, int n)
{
    __shared__ __fp16 sAgg[4][16][80];   // 160B row stride: 16B-aligned b128 reads
    int lane = threadIdx.x & 63;
    int wid  = threadIdx.x >> 6;
    int q = lane >> 4, t = lane & 15;
    int base = blockIdx.x * 64 + wid * 16;

    for (int p = 0; p < 4; ++p) {
        int node  = base + p * 4 + q;
        bool alive = node < n;
        int beg = 0, cnt = 0;
        if (alive) { beg = rp[node]; cnt = rp[node + 1] - beg; }
        unsigned c0 = PKNINF, c1 = PKNINF;
        if (cnt > 0) {
            int pcnt = (cnt + 7) & ~7;
            int e = 0;
            while (e < pcnt) {
                int myc = col[beg + min(e + t, cnt - 1)];
                G8(0);
                if (e + 8 < pcnt) { G8(8); }
                e += 16;
            }
        }
        if (alive) {
            bool has = cnt > 0;
            float4 yi = ((const float4*)y32)[(size_t)node * 16 + t];
            float g0 = has ? (h2lo(c0) - yi.x) : 0.f;
            float g1 = has ? (h2hi(c0) - yi.y) : 0.f;
            float g2 = has ? (h2lo(c1) - yi.z) : 0.f;
            float g3 = has ? (h2hi(c1) - yi.w) : 0.f;
            if (!HEAD) {
                uint2 pk; pk.x = pkrtz(g0, g1); pk.y = pkrtz(g2, g3);
                *(uint2*)&sAgg[wid][p * 4 + q][4 * t] = pk;
            } else {
                float4 vp = ((const float4*)vv)[t];
                float s = g0 * vp.x + g1 * vp.y + g2 * vp.z + g3 * vp.w;
                s += __shfl_xor(s, 8);
                s += __shfl_xor(s, 4);
                s += __shfl_xor(s, 2);
                s += __shfl_xor(s, 1);
                if (t == 0)
                    out[node] = 1.f / (1.f + __expf(-(s + bptr[0])));
            }
        } else if (!HEAD) {
            uint2 z; z.x = 0u; z.y = 0u;
            *(uint2*)&sAgg[wid][p * 4 + q][4 * t] = z;
        }
    }

    if (!HEAD) {
        __syncthreads();
        f16x8 af[4][2];
        #pragma unroll
        for (int dt = 0; dt < 4; ++dt)
            #pragma unroll
            for (int kf = 0; kf < 2; ++kf)
                af[dt][kf] = *(const f16x8*)(W + (size_t)(dt * 16 + t) * 64 + q * 8 + kf * 32);
        f16x8 bf[2];
        #pragma unroll
        for (int kf = 0; kf < 2; ++kf)
            bf[kf] = *(const f16x8*)&sAgg[wid][t][q * 8 + kf * 32];

        int r = base + t;
        int d4 = q * 4;
        #pragma unroll
        for (int dt = 0; dt < 4; ++dt) {
            f32x4 acc = {0.f, 0.f, 0.f, 0.f};
            acc = __builtin_amdgcn_mfma_f32_16x16x32_f16(af[dt][0], bf[0], acc, 0, 0, 0);
            acc = __builtin_amdgcn_mfma_f32_16x16x32_f16(af[dt][1], bf[1], acc, 0, 0, 0);
            if (r < n) {
                int d = dt * 16 + d4;
                float4 o; o.x = acc[0]; o.y = acc[1]; o.z = acc[2]; o.w = acc[3];
                *(float4*)(y32o + (size_t)r * 64 + d) = o;
                uint2 pk; pk.x = pkrtz(acc[0], acc[1]); pk.y = pkrtz(acc[2], acc[3]);
                *(uint2*)(y16o + (size_t)r * 64 + d) = pk;
            }
        }
    }
}

extern "C" void kernel_launch(void* const* d_in, const int* in_sizes, int n_in,
                              void* d_out, int out_size, void* d_ws, size_t ws_size,
                              hipStream_t stream)
{
    const float* x     = (const float*)d_in[0];
    const int*   edges = (const int*)d_in[1];   // int32 view, [2][E]
    const float* Wp    = (const float*)d_in[2];
    const float* Wt    = (const float*)d_in[3];
    const float* Wout  = (const float*)d_in[4];
    const float* bout  = (const float*)d_in[5];
    const int N = in_sizes[0] / 64;             // 100000
    const int E = in_sizes[1] / 2;              // 1600000
    const int NB = (N + WNODES - 1) >> WBITS;   // 196
    float* out = (float*)d_out;

    char* ws = (char*)d_ws;
    float* y32 = (float*)ws; ws += (size_t)N * 64 * 4;
    int*   B1  = (int*)y32;                     // alias: B1 dead before y32 live
    unsigned short* y16A = (unsigned short*)ws; ws += (size_t)N * 64 * 2;
    unsigned short* y16B = (unsigned short*)ws; ws += (size_t)N * 64 * 2;
    int* col     = (int*)ws; ws += (size_t)(E + 8) * 4;
    int* row_ptr = (int*)ws; ws += (size_t)(N + 4) * 4;
    int* bcnt    = (int*)ws; ws += MAXNB * 4;
    int* bbase   = (int*)ws; ws += (MAXNB + 4) * 4;
    int* gcur    = (int*)ws; ws += MAXNB * 4;
    __fp16* Wh = (__fp16*)ws; ws += 3 * 4096 * 2;
    float*  vv = (float*)ws;  ws += 64 * 4;

    const int chunkBlocks = (E + CHUNK - 1) / CHUNK;
    const int gemmBlocks  = ((N + 15) / 16 + 3) / 4;
    const int fusedBlocks = (N + 63) / 64;

    prep_k<<<3, 256, 0, stream>>>(Wp, Wt, Wout, Wh, vv);

    // CSR build (bucketed, write-coalesced)
    clear_int_k<<<1, 256, 0, stream>>>(bcnt, NB);
    bucket_hist_k<<<chunkBlocks, 256, 0, stream>>>(edges, bcnt, E, NB);
    bucket_scan_k<<<1, 256, 0, stream>>>(bcnt, bbase, gcur, row_ptr, NB, N, E);
    partA_k<<<chunkBlocks, 256, 0, stream>>>(edges, gcur, B1, E, NB);
    partB_k<<<NB, 256, 0, stream>>>(B1, bbase, row_ptr, col, N, NB);

    // layer 1 GEMM: x @ Wp0 -> y32, y16A
    gemm_mfma_k<<<gemmBlocks, 256, 0, stream>>>(x, Wh, y32, y16A, N);
    // gather L1 + GEMM L2 -> y32, y16B
    gather_fused_k<false><<<fusedBlocks, 256, 0, stream>>>(
        row_ptr, col, (const uint2*)y16A, y32, Wh + 4096, y32, y16B,
        nullptr, nullptr, nullptr, N);
    // gather L2 + GEMM L3 -> y32, y16A
    gather_fused_k<false><<<fusedBlocks, 256, 0, stream>>>(
        row_ptr, col, (const uint2*)y16B, y32, Wh + 8192, y32, y16A,
        nullptr, nullptr, nullptr, N);
    // gather L3 + head -> out
    gather_fused_k<true><<<fusedBlocks, 256, 0, stream>>>(
        row_ptr, col, (const uint2*)y16A, y32, nullptr, nullptr, nullptr,
        vv, bout, out, N);
}

// Round 10
// 181.171 us; speedup vs baseline: 1.9957x; 1.1326x over previous
//
#include <hip/hip_runtime.h>
#include <math.h>

// ---------------------------------------------------------------------------
// PointSampler / DevConv: CSR-gather (4 nodes/wave, clamp-padded, swizzle
// broadcast) fused with the next layer's MFMA fp16 GEMM. fp16-only state.
//   prep: weights->fp16 (incl. folded C2,C3,v), zero bcnt
//   hist_gemm: blocks<chunkBlocks do dst-bucket histogram; rest do layer-1 GEMM
//   bucket_scan -> partA -> partB  (write-coalesced CSR)
//   fused l: gather(y16) -> LDS agg tile -> MFMA -> y16other
//   final:   gather + Linear(D,1)+sigmoid head
// ---------------------------------------------------------------------------

#define WBITS 9
#define WNODES 512            // nodes per bucket
#define MAXNB 256             // max buckets (requires N <= 131072, src < 2^17)
#define CHUNK 8192            // edges per partA/hist block
#define STG_CAP 12288         // partB LDS staging entries (48 KB)

#define PKNINF 0xFC00FC00u    // packed fp16 (-inf, -inf)

typedef __fp16 h2v __attribute__((ext_vector_type(2)));
typedef _Float16 f16x8 __attribute__((ext_vector_type(8)));
typedef float f32x4 __attribute__((ext_vector_type(4)));

__device__ __forceinline__ unsigned pkmax(unsigned a, unsigned b) {
    unsigned r;
    asm("v_pk_max_f16 %0, %1, %2" : "=v"(r) : "v"(a), "v"(b));
    return r;
}
__device__ __forceinline__ unsigned pkrtz(float a, float b) {
    h2v r = __builtin_amdgcn_cvt_pkrtz(a, b);
    return *reinterpret_cast<unsigned*>(&r);
}
__device__ __forceinline__ float h2lo(unsigned u) {
    h2v h = *reinterpret_cast<h2v*>(&u);
    return (float)h.x;
}
__device__ __forceinline__ float h2hi(unsigned u) {
    h2v h = *reinterpret_cast<h2v*>(&u);
    return (float)h.y;
}

// 8 edges: broadcast col idx from quarter-lane K0+k, load 8B of fp16 row, pkmax
#define G8(K0) do { \
    int j0 = __builtin_amdgcn_ds_swizzle(myc, (((K0)+0)<<5)|0x10); \
    int j1 = __builtin_amdgcn_ds_swizzle(myc, (((K0)+1)<<5)|0x10); \
    int j2 = __builtin_amdgcn_ds_swizzle(myc, (((K0)+2)<<5)|0x10); \
    int j3 = __builtin_amdgcn_ds_swizzle(myc, (((K0)+3)<<5)|0x10); \
    int j4 = __builtin_amdgcn_ds_swizzle(myc, (((K0)+4)<<5)|0x10); \
    int j5 = __builtin_amdgcn_ds_swizzle(myc, (((K0)+5)<<5)|0x10); \
    int j6 = __builtin_amdgcn_ds_swizzle(myc, (((K0)+6)<<5)|0x10); \
    int j7 = __builtin_amdgcn_ds_swizzle(myc, (((K0)+7)<<5)|0x10); \
    uint2 w0 = y16[(size_t)j0 * 16 + t]; \
    uint2 w1 = y16[(size_t)j1 * 16 + t]; \
    uint2 w2 = y16[(size_t)j2 * 16 + t]; \
    uint2 w3 = y16[(size_t)j3 * 16 + t]; \
    uint2 w4 = y16[(size_t)j4 * 16 + t]; \
    uint2 w5 = y16[(size_t)j5 * 16 + t]; \
    uint2 w6 = y16[(size_t)j6 * 16 + t]; \
    uint2 w7 = y16[(size_t)j7 * 16 + t]; \
    c0 = pkmax(c0, pkmax(pkmax(pkmax(w0.x, w1.x), pkmax(w2.x, w3.x)), \
                         pkmax(pkmax(w4.x, w5.x), pkmax(w6.x, w7.x)))); \
    c1 = pkmax(c1, pkmax(pkmax(pkmax(w0.y, w1.y), pkmax(w2.y, w3.y)), \
                         pkmax(pkmax(w4.y, w5.y), pkmax(w6.y, w7.y)))); \
} while (0)

// block 0: Wh1 = fp16(Wp[1]@Wt[0]) + zero bcnt; block 1: Wh2 = fp16(Wp[2]@Wt[1]);
// block 2: vv = Wout@Wt[2] (f32) and Wh0 = fp16(Wp[0])
__global__ __launch_bounds__(256) void prep_k(
    const float* __restrict__ Wp, const float* __restrict__ Wt,
    const float* __restrict__ Wout,
    __fp16* __restrict__ Wh, float* __restrict__ vout,
    int* __restrict__ bcnt)
{
    __shared__ float A[4096];
    __shared__ float B[4096];
    int tid = threadIdx.x;
    int b = blockIdx.x;
    if (b < 2) {
        if (b == 0 && tid < MAXNB) bcnt[tid] = 0;
        const float* Ap = Wp + (size_t)(b + 1) * 4096;
        const float* Bp = Wt + (size_t)b * 4096;
        for (int i = tid; i < 4096; i += 256) { A[i] = Ap[i]; B[i] = Bp[i]; }
        __syncthreads();
        __fp16* C = Wh + (size_t)(b + 1) * 4096;
        for (int i = tid; i < 4096; i += 256) {
            int d = i >> 6, k = i & 63;
            float s = 0.f;
            #pragma unroll
            for (int m = 0; m < 64; ++m) s += A[d * 64 + m] * B[m * 64 + k];
            C[i] = (__fp16)s;
        }
    } else {
        for (int i = tid; i < 4096; i += 256) {
            A[i] = Wt[2 * 4096 + i];
            Wh[i] = (__fp16)Wp[i];
        }
        if (tid < 64) B[tid] = Wout[tid];
        __syncthreads();
        if (tid < 64) {
            float s = 0.f;
            #pragma unroll
            for (int m = 0; m < 64; ++m) s += B[m] * A[m * 64 + tid];
            vout[tid] = s;
        }
    }
}

// blocks [0, chunkBlocks): per-chunk LDS histogram of dst buckets.
// blocks [chunkBlocks, ...): layer-1 MFMA GEMM  y16 = fp16(x @ Wh0.T).
__global__ __launch_bounds__(256) void hist_gemm_k(
    const int* __restrict__ eidx, int* __restrict__ bcnt, int E, int NB,
    int chunkBlocks,
    const float* __restrict__ xin, const __fp16* __restrict__ W,
    unsigned short* __restrict__ y16o, int n)
{
    __shared__ int h[MAXNB];
    int tid = threadIdx.x;
    if (blockIdx.x < chunkBlocks) {
        for (int i = tid; i < NB; i += 256) h[i] = 0;
        __syncthreads();
        int start = blockIdx.x * CHUNK;
        int end = min(E, start + CHUNK);
        for (int e = start + tid; e < end; e += 256)
            atomicAdd(&h[eidx[E + e] >> WBITS], 1);
        __syncthreads();
        for (int i = tid; i < NB; i += 256)
            if (h[i]) atomicAdd(&bcnt[i], h[i]);
    } else {
        int lane = tid & 63;
        int wid  = tid >> 6;
        int r0   = ((blockIdx.x - chunkBlocks) * 4 + wid) * 16;
        if (r0 >= n) return;
        int l15 = lane & 15;
        int ko  = (lane >> 4) * 8;

        f16x8 af[4][2];
        #pragma unroll
        for (int dt = 0; dt < 4; ++dt)
            #pragma unroll
            for (int kf = 0; kf < 2; ++kf)
                af[dt][kf] = *(const f16x8*)(W + (size_t)(dt * 16 + l15) * 64 + ko + kf * 32);

        f16x8 bf[2];
        int rr = min(r0 + l15, n - 1);
        #pragma unroll
        for (int kf = 0; kf < 2; ++kf) {
            const float4* p = (const float4*)(xin + (size_t)rr * 64 + ko + kf * 32);
            float4 a = p[0], b = p[1];
            union { uint4 u; f16x8 hh; } cv;
            cv.u.x = pkrtz(a.x, a.y); cv.u.y = pkrtz(a.z, a.w);
            cv.u.z = pkrtz(b.x, b.y); cv.u.w = pkrtz(b.z, b.w);
            bf[kf] = cv.hh;
        }

        int r = r0 + l15;
        int d4 = (lane >> 4) * 4;
        #pragma unroll
        for (int dt = 0; dt < 4; ++dt) {
            f32x4 acc = {0.f, 0.f, 0.f, 0.f};
            acc = __builtin_amdgcn_mfma_f32_16x16x32_f16(af[dt][0], bf[0], acc, 0, 0, 0);
            acc = __builtin_amdgcn_mfma_f32_16x16x32_f16(af[dt][1], bf[1], acc, 0, 0, 0);
            if (r < n) {
                uint2 p; p.x = pkrtz(acc[0], acc[1]); p.y = pkrtz(acc[2], acc[3]);
                *(uint2*)(y16o + (size_t)r * 64 + dt * 16 + d4) = p;
            }
        }
    }
}

// 1-block scan of bucket counts -> bbase (exclusive), init gcur, row_ptr[N]=E
__global__ __launch_bounds__(256) void bucket_scan_k(
    const int* __restrict__ bcnt, int* __restrict__ bbase,
    int* __restrict__ gcur, int* __restrict__ row_ptr, int NB, int N, int E)
{
    __shared__ int sA[MAXNB], sB[MAXNB];
    int tid = threadIdx.x;
    int v0 = (tid < NB) ? bcnt[tid] : 0;
    sA[tid] = v0;
    __syncthreads();
    int* sp = sA; int* dp = sB;
    for (int off = 1; off < MAXNB; off <<= 1) {
        dp[tid] = sp[tid] + ((tid >= off) ? sp[tid - off] : 0);
        __syncthreads();
        int* t = sp; sp = dp; dp = t;
    }
    if (tid < NB) {
        int ex = sp[tid] - v0;
        bbase[tid] = ex;
        gcur[tid]  = ex;
    }
    if (tid == 0) {
        bbase[NB]  = E;
        row_ptr[N] = E;
    }
}

// partition edges into bucket-major order (packed src | dstLow<<17)
__global__ __launch_bounds__(256) void partA_k(
    const int* __restrict__ eidx, int* __restrict__ gcur,
    int* __restrict__ B1, int E, int NB)
{
    __shared__ int hist[MAXNB];
    __shared__ int lofs[MAXNB];
    __shared__ int lcur[MAXNB];
    __shared__ int gofs[MAXNB];
    __shared__ int sA[MAXNB], sB[MAXNB];
    __shared__ int stg_val[CHUNK];
    __shared__ int stg_pos[CHUNK];
    int tid = threadIdx.x;
    int start = blockIdx.x * CHUNK;
    int cnt = min(E - start, CHUNK);
    if (cnt <= 0) return;

    for (int i = tid; i < NB; i += 256) hist[i] = 0;
    __syncthreads();

    int es[CHUNK / 256], ed[CHUNK / 256];
    #pragma unroll
    for (int i = 0; i < CHUNK / 256; ++i) {
        int li = i * 256 + tid;
        if (li < cnt) {
            es[i] = eidx[start + li];
            ed[i] = eidx[E + start + li];
            atomicAdd(&hist[ed[i] >> WBITS], 1);
        }
    }
    __syncthreads();
    sA[tid] = (tid < NB) ? hist[tid] : 0;
    __syncthreads();
    int* sp = sA; int* dp = sB;
    for (int off = 1; off < MAXNB; off <<= 1) {
        dp[tid] = sp[tid] + ((tid >= off) ? sp[tid - off] : 0);
        __syncthreads();
        int* t = sp; sp = dp; dp = t;
    }
    if (tid < NB) {
        int c  = hist[tid];
        int ex = sp[tid] - c;
        lofs[tid] = ex;
        lcur[tid] = ex;
        gofs[tid] = c ? atomicAdd(&gcur[tid], c) : 0;
    }
    __syncthreads();
    #pragma unroll
    for (int i = 0; i < CHUNK / 256; ++i) {
        int li = i * 256 + tid;
        if (li < cnt) {
            int b = ed[i] >> WBITS;
            int p = atomicAdd(&lcur[b], 1);
            stg_val[p] = es[i] | ((ed[i] & (WNODES - 1)) << 17);
            stg_pos[p] = gofs[b] + (p - lofs[b]);
        }
    }
    __syncthreads();
    for (int i = tid; i < cnt; i += 256)
        B1[stg_pos[i]] = stg_val[i];
}

// per-bucket: degree count -> scan -> row_ptr; LDS-staged coalesced col scatter
__global__ __launch_bounds__(256) void partB_k(
    const int* __restrict__ B1, const int* __restrict__ bbase,
    int* __restrict__ row_ptr, int* __restrict__ col, int N, int NB)
{
    __shared__ int cnt[WNODES];
    __shared__ int lcur[WNODES];
    __shared__ int sA[WNODES], sB[WNODES];
    __shared__ int stg[STG_CAP];
    int b   = blockIdx.x;
    int tid = threadIdx.x;
    int gb0 = bbase[b], gb1 = bbase[b + 1];
    int m   = gb1 - gb0;
    int nb0 = b << WBITS;

    for (int i = tid; i < WNODES; i += 256) cnt[i] = 0;
    __syncthreads();
    for (int i = tid; i < m; i += 256)
        atomicAdd(&cnt[B1[gb0 + i] >> 17], 1);
    __syncthreads();
    for (int i = tid; i < WNODES; i += 256) sA[i] = cnt[i];
    __syncthreads();
    int* sp = sA; int* dp = sB;
    for (int off = 1; off < WNODES; off <<= 1) {
        for (int i = tid; i < WNODES; i += 256)
            dp[i] = sp[i] + ((i >= off) ? sp[i - off] : 0);
        __syncthreads();
        int* t = sp; sp = dp; dp = t;
    }
    for (int i = tid; i < WNODES; i += 256) {
        int ex = sp[i] - cnt[i];
        lcur[i] = ex;
        int node = nb0 + i;
        if (node < N) row_ptr[node] = gb0 + ex;
    }
    __syncthreads();
    if (m <= STG_CAP) {
        for (int i = tid; i < m; i += 256) {
            int v = B1[gb0 + i];
            int p = atomicAdd(&lcur[v >> 17], 1);
            stg[p] = v & 0x1FFFF;
        }
        __syncthreads();
        for (int i = tid; i < m; i += 256)
            col[gb0 + i] = stg[i];
    } else {               // adversarial-degree fallback (correct, uncoalesced)
        for (int i = tid; i < m; i += 256) {
            int v = B1[gb0 + i];
            int p = atomicAdd(&lcur[v >> 17], 1);
            col[gb0 + p] = v & 0x1FFFF;
        }
    }
}

// ---------------- fused gather (+ next-layer GEMM | head) ----------------
// Wave = 4 nodes/pass x 4 passes = 16 nodes; quarter q owns a node, lane t
// holds comps [4t,4t+4) as uint2. Edges clamp-padded to multiple of 8 (dup of
// last neighbor; cache-hot). ds_swizzle broadcasts col indices (MLP 8).
// Subtraction uses the node's own fp16 row (no f32 mirror).
// HEAD=false: agg -> LDS tile -> per-wave 16-row MFMA -> y16o.
// HEAD=true:  agg . v + b -> sigmoid -> out.
template<bool HEAD>
__global__ __launch_bounds__(256) void gather_fused_k(
    const int* __restrict__ rp, const int* __restrict__ col,
    const uint2* __restrict__ y16,
    const __fp16* __restrict__ W,
    unsigned short* __restrict__ y16o,
    const float* __restrict__ vv, const float* __restrict__ bptr,
    float* __restrict__ out, int n)
{
    __shared__ __fp16 sAgg[4][16][80];   // 160B row stride: 16B-aligned b128 reads
    int lane = threadIdx.x & 63;
    int wid  = threadIdx.x >> 6;
    int q = lane >> 4, t = lane & 15;
    int base = blockIdx.x * 64 + wid * 16;

    for (int p = 0; p < 4; ++p) {
        int node  = base + p * 4 + q;
        bool alive = node < n;
        int beg = 0, cnt = 0;
        if (alive) { beg = rp[node]; cnt = rp[node + 1] - beg; }
        unsigned c0 = PKNINF, c1 = PKNINF;
        if (cnt > 0) {
            int pcnt = (cnt + 7) & ~7;
            int e = 0;
            while (e < pcnt) {
                int myc = col[beg + min(e + t, cnt - 1)];
                G8(0);
                if (e + 8 < pcnt) { G8(8); }
                e += 16;
            }
        }
        if (alive) {
            bool has = cnt > 0;
            uint2 yi2 = y16[(size_t)node * 16 + t];
            float g0 = has ? (h2lo(c0) - h2lo(yi2.x)) : 0.f;
            float g1 = has ? (h2hi(c0) - h2hi(yi2.x)) : 0.f;
            float g2 = has ? (h2lo(c1) - h2lo(yi2.y)) : 0.f;
            float g3 = has ? (h2hi(c1) - h2hi(yi2.y)) : 0.f;
            if (!HEAD) {
                uint2 pk; pk.x = pkrtz(g0, g1); pk.y = pkrtz(g2, g3);
                *(uint2*)&sAgg[wid][p * 4 + q][4 * t] = pk;
            } else {
                float4 vp = ((const float4*)vv)[t];
                float s = g0 * vp.x + g1 * vp.y + g2 * vp.z + g3 * vp.w;
                s += __shfl_xor(s, 8);
                s += __shfl_xor(s, 4);
                s += __shfl_xor(s, 2);
                s += __shfl_xor(s, 1);
                if (t == 0)
                    out[node] = 1.f / (1.f + __expf(-(s + bptr[0])));
            }
        } else if (!HEAD) {
            uint2 z; z.x = 0u; z.y = 0u;
            *(uint2*)&sAgg[wid][p * 4 + q][4 * t] = z;
        }
    }

    if (!HEAD) {
        __syncthreads();
        f16x8 af[4][2];
        #pragma unroll
        for (int dt = 0; dt < 4; ++dt)
            #pragma unroll
            for (int kf = 0; kf < 2; ++kf)
                af[dt][kf] = *(const f16x8*)(W + (size_t)(dt * 16 + t) * 64 + q * 8 + kf * 32);
        f16x8 bf[2];
        #pragma unroll
        for (int kf = 0; kf < 2; ++kf)
            bf[kf] = *(const f16x8*)&sAgg[wid][t][q * 8 + kf * 32];

        int r = base + t;
        int d4 = q * 4;
        #pragma unroll
        for (int dt = 0; dt < 4; ++dt) {
            f32x4 acc = {0.f, 0.f, 0.f, 0.f};
            acc = __builtin_amdgcn_mfma_f32_16x16x32_f16(af[dt][0], bf[0], acc, 0, 0, 0);
            acc = __builtin_amdgcn_mfma_f32_16x16x32_f16(af[dt][1], bf[1], acc, 0, 0, 0);
            if (r < n) {
                uint2 pk; pk.x = pkrtz(acc[0], acc[1]); pk.y = pkrtz(acc[2], acc[3]);
                *(uint2*)(y16o + (size_t)r * 64 + dt * 16 + d4) = pk;
            }
        }
    }
}

extern "C" void kernel_launch(void* const* d_in, const int* in_sizes, int n_in,
                              void* d_out, int out_size, void* d_ws, size_t ws_size,
                              hipStream_t stream)
{
    const float* x     = (const float*)d_in[0];
    const int*   edges = (const int*)d_in[1];   // int32 view, [2][E]
    const float* Wp    = (const float*)d_in[2];
    const float* Wt    = (const float*)d_in[3];
    const float* Wout  = (const float*)d_in[4];
    const float* bout  = (const float*)d_in[5];
    const int N = in_sizes[0] / 64;             // 100000
    const int E = in_sizes[1] / 2;              // 1600000
    const int NB = (N + WNODES - 1) >> WBITS;   // 196
    float* out = (float*)d_out;

    char* ws = (char*)d_ws;
    unsigned short* y16A = (unsigned short*)ws; ws += (size_t)N * 64 * 2;
    unsigned short* y16B = (unsigned short*)ws; ws += (size_t)N * 64 * 2;
    int*   B1  = (int*)y16B;                    // alias: B1 dead before y16B live
    int* col     = (int*)ws; ws += (size_t)(E + 8) * 4;
    int* row_ptr = (int*)ws; ws += (size_t)(N + 4) * 4;
    int* bcnt    = (int*)ws; ws += MAXNB * 4;
    int* bbase   = (int*)ws; ws += (MAXNB + 4) * 4;
    int* gcur    = (int*)ws; ws += MAXNB * 4;
    __fp16* Wh = (__fp16*)ws; ws += 3 * 4096 * 2;
    float*  vv = (float*)ws;  ws += 64 * 4;

    const int chunkBlocks = (E + CHUNK - 1) / CHUNK;           // 196
    const int gemmBlocks  = ((N + 15) / 16 + 3) / 4;           // 1563
    const int fusedBlocks = (N + 63) / 64;                     // 1563

    prep_k<<<3, 256, 0, stream>>>(Wp, Wt, Wout, Wh, vv, bcnt);

    // hist (blocks<chunkBlocks) + layer-1 GEMM (rest), overlapped
    hist_gemm_k<<<chunkBlocks + gemmBlocks, 256, 0, stream>>>(
        edges, bcnt, E, NB, chunkBlocks, x, Wh, y16A, N);
    bucket_scan_k<<<1, 256, 0, stream>>>(bcnt, bbase, gcur, row_ptr, NB, N, E);
    partA_k<<<chunkBlocks, 256, 0, stream>>>(edges, gcur, B1, E, NB);
    partB_k<<<NB, 256, 0, stream>>>(B1, bbase, row_ptr, col, N, NB);

    // gather L1 + GEMM L2 -> y16B
    gather_fused_k<false><<<fusedBlocks, 256, 0, stream>>>(
        row_ptr, col, (const uint2*)y16A, Wh + 4096, y16B,
        nullptr, nullptr, nullptr, N);
    // gather L2 + GEMM L3 -> y16A
    gather_fused_k<false><<<fusedBlocks, 256, 0, stream>>>(
        row_ptr, col, (const uint2*)y16B, Wh + 8192, y16A,
        nullptr, nullptr, nullptr, N);
    // gather L3 + head -> out
    gather_fused_k<true><<<fusedBlocks, 256, 0, stream>>>(
        row_ptr, col, (const uint2*)y16A, nullptr, nullptr,
        vv, bout, out, N);
}